// Round 1
// baseline (368.088 us; speedup 1.0000x reference)
//
#include <hip/hip_runtime.h>

// Causal MHA with variable-length masking, bf16 MFMA pipeline.
// B=4 S=2048 D=1024 H=16 HD=64. Output f32 [B,S,D].

typedef __attribute__((ext_vector_type(8))) short bf16x8;
typedef __attribute__((ext_vector_type(4))) float f32x4;

static __device__ __forceinline__ short f2bf(float f) {
    union { float f; unsigned u; } x; x.f = f;
    unsigned r = (x.u + 0x7FFFu + ((x.u >> 16) & 1u)) >> 16;   // RNE
    return (short)r;
}

constexpr int Bc = 4, Sc = 2048, Dc = 1024, Hc = 16, HDc = 64;
constexpr int Mrows = Bc * Sc;           // 8192
constexpr int LDK = 72;                  // padded LDS leading dim (bf16 elems)

// ---------------- prep kernels ----------------

__global__ void cast_x_kernel(const float* __restrict__ x, short* __restrict__ xb) {
    int i = blockIdx.x * blockDim.x + threadIdx.x;   // 1M threads, 8 elems each
    const float4* xin = (const float4*)x;
    float4 a = xin[i * 2 + 0];
    float4 b = xin[i * 2 + 1];
    bf16x8 o;
    o[0] = f2bf(a.x); o[1] = f2bf(a.y); o[2] = f2bf(a.z); o[3] = f2bf(a.w);
    o[4] = f2bf(b.x); o[5] = f2bf(b.y); o[6] = f2bf(b.z); o[7] = f2bf(b.w);
    *(bf16x8*)&xb[(size_t)i * 8] = o;
}

// W [k][n] f32 -> Wt [n][k] bf16 (per matrix), 64x64 tiles via LDS
__global__ void transpose_w_kernel(const float* __restrict__ W0, const float* __restrict__ W1,
                                   const float* __restrict__ W2, const float* __restrict__ W3,
                                   short* __restrict__ Wt) {
    __shared__ float tile[64][65];
    const float* W = blockIdx.z == 0 ? W0 : blockIdx.z == 1 ? W1 : blockIdx.z == 2 ? W2 : W3;
    short* out = Wt + (size_t)blockIdx.z * Dc * Dc;
    int k0 = blockIdx.y * 64, n0 = blockIdx.x * 64;
    int t = threadIdx.x;
#pragma unroll
    for (int i = 0; i < 4; i++) {
        int c = t + i * 256; int r = c >> 4, cc = (c & 15) * 4;
        float4 v = *(const float4*)&W[(size_t)(k0 + r) * Dc + n0 + cc];
        tile[r][cc + 0] = v.x; tile[r][cc + 1] = v.y;
        tile[r][cc + 2] = v.z; tile[r][cc + 3] = v.w;
    }
    __syncthreads();
#pragma unroll
    for (int i = 0; i < 2; i++) {
        int c = t + i * 256; int nn = c >> 3, kc = (c & 7) * 8;
        bf16x8 o;
#pragma unroll
        for (int j = 0; j < 8; j++) o[j] = f2bf(tile[kc + j][nn]);
        *(bf16x8*)&out[(size_t)(n0 + nn) * Dc + k0 + kc] = o;
    }
}

// valid_mask (bool8 / int32 / float32 on the wire) -> u8. Probe word 0: batch 0 row 0 is valid.
__global__ void mask_kernel(const unsigned int* __restrict__ m, unsigned char* __restrict__ mask8) {
    int i = blockIdx.x * blockDim.x + threadIdx.x;   // 8192 threads
    unsigned w0 = m[0];
    unsigned char v;
    if (w0 == 1u)                 v = (unsigned char)(m[i] != 0);          // int32
    else if (w0 == 0x01010101u)   v = ((const unsigned char*)m)[i];        // bool (1B)
    else                          v = (((const float*)m)[i] != 0.0f);      // float32
    mask8[i] = v ? 1 : 0;
}

// ---------------- GEMM: C[M,N] = A[M,K] @ Wt[N,K]^T, K=N=1024 ----------------
// MODE 0: store bf16 to [B,H,S,HD] (QKV head split). MODE 1: +bias, row-mask, f32 out.
template <int MODE>
__global__ __launch_bounds__(256, 2) void gemm_bt(
    const short* __restrict__ A, const short* __restrict__ Bt,
    const float* __restrict__ bias, const unsigned char* __restrict__ mask,
    short* __restrict__ outb, float* __restrict__ outf) {
    constexpr int K = 1024, N = 1024;
    __shared__ short la[128 * LDK];
    __shared__ short lb[128 * LDK];
    int bid = blockIdx.x;
    int tm = bid >> 3, tn = bid & 7;               // N/128 = 8
    int brow = tm * 128, bcol = tn * 128;
    int t = threadIdx.x;
    int w = t >> 6, l = t & 63;
    int wr = w >> 1, wc = w & 1;                   // wave quadrant (64x64)
    int lr = l & 15, lg = l >> 4;

    f32x4 zero4 = {0.f, 0.f, 0.f, 0.f};
    f32x4 acc[4][4];
#pragma unroll
    for (int mi = 0; mi < 4; mi++)
#pragma unroll
        for (int ni = 0; ni < 4; ni++) acc[mi][ni] = zero4;

    bf16x8 ra[4], rb[4];
#pragma unroll
    for (int i = 0; i < 4; i++) {                  // preload K-step 0
        int c = t + i * 256; int r = c >> 3, cc = (c & 7) * 8;
        ra[i] = *(const bf16x8*)&A [(size_t)(brow + r) * K + cc];
        rb[i] = *(const bf16x8*)&Bt[(size_t)(bcol + r) * K + cc];
    }

    for (int kt = 0; kt < K; kt += 64) {
        __syncthreads();                           // prev compute done
#pragma unroll
        for (int i = 0; i < 4; i++) {
            int c = t + i * 256; int r = c >> 3, cc = (c & 7) * 8;
            *(bf16x8*)&la[r * LDK + cc] = ra[i];
            *(bf16x8*)&lb[r * LDK + cc] = rb[i];
        }
        __syncthreads();
        if (kt + 64 < K) {                         // prefetch next K-step into regs
#pragma unroll
            for (int i = 0; i < 4; i++) {
                int c = t + i * 256; int r = c >> 3, cc = (c & 7) * 8;
                ra[i] = *(const bf16x8*)&A [(size_t)(brow + r) * K + kt + 64 + cc];
                rb[i] = *(const bf16x8*)&Bt[(size_t)(bcol + r) * K + kt + 64 + cc];
            }
        }
#pragma unroll
        for (int kk = 0; kk < 2; kk++) {
            bf16x8 af[4], bfr[4];
#pragma unroll
            for (int mi = 0; mi < 4; mi++)
                af[mi] = *(const bf16x8*)&la[(wr * 64 + mi * 16 + lr) * LDK + kk * 32 + lg * 8];
#pragma unroll
            for (int ni = 0; ni < 4; ni++)
                bfr[ni] = *(const bf16x8*)&lb[(wc * 64 + ni * 16 + lr) * LDK + kk * 32 + lg * 8];
#pragma unroll
            for (int mi = 0; mi < 4; mi++)
#pragma unroll
                for (int ni = 0; ni < 4; ni++)
                    acc[mi][ni] = __builtin_amdgcn_mfma_f32_16x16x32_bf16(
                        af[mi], bfr[ni], acc[mi][ni], 0, 0, 0);
        }
    }

    // D layout: row = lg*4 + r, col = lr  (verified m89/m91)
#pragma unroll
    for (int mi = 0; mi < 4; mi++)
#pragma unroll
        for (int ni = 0; ni < 4; ni++)
#pragma unroll
            for (int r = 0; r < 4; r++) {
                int m = brow + wr * 64 + mi * 16 + lg * 4 + r;
                int n = bcol + wc * 64 + ni * 16 + lr;
                float v = acc[mi][ni][r];
                if (MODE == 0) {
                    int b = m >> 11, s = m & 2047, h = n >> 6, hd = n & 63;
                    outb[((size_t)(b * Hc + h) * Sc + s) * HDc + hd] = f2bf(v);
                } else {
                    v += bias[n];
                    if (!mask[m]) v = 0.f;
                    outf[(size_t)m * N + n] = v;
                }
            }
}

// ---------------- flash attention (pure causal; mask handled in Wo epilogue) ----------------
// grid: (b*H+h)*16 + qtile. 4 waves x 32 q-rows = 128 q-rows/block. KBLK=64.
__global__ __launch_bounds__(256, 2) void attn_kernel(
    const short* __restrict__ Q, const short* __restrict__ Kp,
    const short* __restrict__ Vp, short* __restrict__ ctx) {
    __shared__ short lk[64 * LDK];                 // K tile [key][hd]
    __shared__ short lv[64 * LDK];                 // V tile transposed [hd][key]
    __shared__ short lp[4][32 * LDK];              // per-wave P [qrow][key]
    int bid = blockIdx.x;
    int qt = bid & 15, bh = bid >> 4;
    const short* qp = Q  + (size_t)bh * Sc * HDc;
    const short* kp = Kp + (size_t)bh * Sc * HDc;
    const short* vp = Vp + (size_t)bh * Sc * HDc;
    int qbase = qt * 128;
    int t = threadIdx.x, w = t >> 6, l = t & 63;
    int lr = l & 15, lg = l >> 4;
    int wq = qbase + w * 32;                       // this wave's q rows [wq, wq+32)

    bf16x8 qf[2][2];
#pragma unroll
    for (int mi = 0; mi < 2; mi++)
#pragma unroll
        for (int kk = 0; kk < 2; kk++)
            qf[mi][kk] = *(const bf16x8*)&qp[(size_t)(wq + mi * 16 + lr) * HDc + kk * 32 + lg * 8];

    f32x4 zero4 = {0.f, 0.f, 0.f, 0.f};
    f32x4 o[2][4];
    float mrow[2][4], lrow[2][4];
#pragma unroll
    for (int mi = 0; mi < 2; mi++) {
#pragma unroll
        for (int ni = 0; ni < 4; ni++) o[mi][ni] = zero4;
#pragma unroll
        for (int r = 0; r < 4; r++) { mrow[mi][r] = -1e30f; lrow[mi][r] = 0.f; }
    }

    int nt = qbase / 64 + 2;                       // causal tile count for this block
    bf16x8 rk[2], rv[2];
#pragma unroll
    for (int i = 0; i < 2; i++) {                  // preload tile 0
        int c = t + i * 256; int r = c >> 3, cc = (c & 7) * 8;
        rk[i] = *(const bf16x8*)&kp[(size_t)r * HDc + cc];
        rv[i] = *(const bf16x8*)&vp[(size_t)r * HDc + cc];
    }

    for (int tk = 0; tk < nt; tk++) {
        int k0 = tk * 64;
        __syncthreads();
#pragma unroll
        for (int i = 0; i < 2; i++) {
            int c = t + i * 256; int r = c >> 3, cc = (c & 7) * 8;
            *(bf16x8*)&lk[r * LDK + cc] = rk[i];
#pragma unroll
            for (int j = 0; j < 8; j++) lv[(cc + j) * LDK + r] = rv[i][j];   // transpose V
        }
        __syncthreads();
        if (tk + 1 < nt) {
#pragma unroll
            for (int i = 0; i < 2; i++) {
                int c = t + i * 256; int r = c >> 3, cc = (c & 7) * 8;
                rk[i] = *(const bf16x8*)&kp[(size_t)(k0 + 64 + r) * HDc + cc];
                rv[i] = *(const bf16x8*)&vp[(size_t)(k0 + 64 + r) * HDc + cc];
            }
        }
        if (k0 <= wq + 31) {                       // wave-uniform causal skip
            // S = Q K^T
            f32x4 s[2][4];
#pragma unroll
            for (int mi = 0; mi < 2; mi++)
#pragma unroll
                for (int ni = 0; ni < 4; ni++) s[mi][ni] = zero4;
            bf16x8 kf[4][2];
#pragma unroll
            for (int ni = 0; ni < 4; ni++)
#pragma unroll
                for (int kk = 0; kk < 2; kk++)
                    kf[ni][kk] = *(const bf16x8*)&lk[(ni * 16 + lr) * LDK + kk * 32 + lg * 8];
#pragma unroll
            for (int mi = 0; mi < 2; mi++)
#pragma unroll
                for (int ni = 0; ni < 4; ni++)
#pragma unroll
                    for (int kk = 0; kk < 2; kk++)
                        s[mi][ni] = __builtin_amdgcn_mfma_f32_16x16x32_bf16(
                            qf[mi][kk], kf[ni][kk], s[mi][ni], 0, 0, 0);
            // online softmax: row = wq + mi*16 + lg*4 + r, col/key = k0 + ni*16 + lr
            float corr[2][4];
#pragma unroll
            for (int mi = 0; mi < 2; mi++)
#pragma unroll
                for (int r = 0; r < 4; r++) {
                    int qrow = wq + mi * 16 + lg * 4 + r;
                    float mx = -1e30f;
#pragma unroll
                    for (int ni = 0; ni < 4; ni++) {
                        int key = k0 + ni * 16 + lr;
                        float sv = s[mi][ni][r] * 0.125f;    // 1/sqrt(64)
                        if (key > qrow) sv = -1e30f;
                        s[mi][ni][r] = sv;
                        mx = fmaxf(mx, sv);
                    }
                    for (int d = 1; d < 16; d <<= 1) mx = fmaxf(mx, __shfl_xor(mx, d, 64));
                    float mnew = fmaxf(mrow[mi][r], mx);
                    corr[mi][r] = __expf(mrow[mi][r] - mnew);
                    mrow[mi][r] = mnew;
                    float sum = 0.f;
#pragma unroll
                    for (int ni = 0; ni < 4; ni++) {
                        float p = __expf(s[mi][ni][r] - mnew);
                        s[mi][ni][r] = p;
                        sum += p;
                    }
                    for (int d = 1; d < 16; d <<= 1) sum += __shfl_xor(sum, d, 64);
                    lrow[mi][r] = lrow[mi][r] * corr[mi][r] + sum;
                }
            // P -> LDS (bf16), rescale O
#pragma unroll
            for (int mi = 0; mi < 2; mi++)
#pragma unroll
                for (int ni = 0; ni < 4; ni++)
#pragma unroll
                    for (int r = 0; r < 4; r++)
                        lp[w][(mi * 16 + lg * 4 + r) * LDK + ni * 16 + lr] = f2bf(s[mi][ni][r]);
#pragma unroll
            for (int mi = 0; mi < 2; mi++)
#pragma unroll
                for (int ni = 0; ni < 4; ni++)
#pragma unroll
                    for (int r = 0; r < 4; r++) o[mi][ni][r] *= corr[mi][r];
            // O += P V
            bf16x8 pa[2][2], vbf[4][2];
#pragma unroll
            for (int mi = 0; mi < 2; mi++)
#pragma unroll
                for (int kk = 0; kk < 2; kk++)
                    pa[mi][kk] = *(const bf16x8*)&lp[w][(mi * 16 + lr) * LDK + kk * 32 + lg * 8];
#pragma unroll
            for (int ni = 0; ni < 4; ni++)
#pragma unroll
                for (int kk = 0; kk < 2; kk++)
                    vbf[ni][kk] = *(const bf16x8*)&lv[(ni * 16 + lr) * LDK + kk * 32 + lg * 8];
#pragma unroll
            for (int mi = 0; mi < 2; mi++)
#pragma unroll
                for (int ni = 0; ni < 4; ni++)
#pragma unroll
                    for (int kk = 0; kk < 2; kk++)
                        o[mi][ni] = __builtin_amdgcn_mfma_f32_16x16x32_bf16(
                            pa[mi][kk], vbf[ni][kk], o[mi][ni], 0, 0, 0);
        }
    }
    // epilogue: ctx[b*S+s][h*64+hd] bf16
    int b = bh >> 4, h = bh & 15;
#pragma unroll
    for (int mi = 0; mi < 2; mi++)
#pragma unroll
        for (int ni = 0; ni < 4; ni++)
#pragma unroll
            for (int r = 0; r < 4; r++) {
                int srow = wq + mi * 16 + lg * 4 + r;
                float v = o[mi][ni][r] / lrow[mi][r];
                ctx[(size_t)(b * Sc + srow) * Dc + h * 64 + ni * 16 + lr] = f2bf(v);
            }
}

// ---------------- launch ----------------

extern "C" void kernel_launch(void* const* d_in, const int* in_sizes, int n_in,
                              void* d_out, int out_size, void* d_ws, size_t ws_size,
                              hipStream_t stream) {
    (void)in_sizes; (void)n_in; (void)out_size; (void)ws_size;
    const float* x  = (const float*)d_in[0];
    const float* Wq = (const float*)d_in[1];
    const float* Wk = (const float*)d_in[2];
    const float* Wv = (const float*)d_in[3];
    const float* Wo = (const float*)d_in[4];
    const float* bo = (const float*)d_in[5];
    const unsigned int* vm = (const unsigned int*)d_in[6];

    char* ws = (char*)d_ws;
    short* xb  = (short*)(ws);                       // 16 MB  x bf16 [8192][1024]
    short* Wt  = (short*)(ws + (16u << 20));         //  8 MB  Wt bf16 [4][1024][1024]
    short* qb  = (short*)(ws + (24u << 20));         // 16 MB  [B,H,S,HD]
    short* kb  = (short*)(ws + (40u << 20));         // 16 MB
    short* vb  = (short*)(ws + (56u << 20));         // 16 MB
    short* ctx = (short*)(ws + (72u << 20));         // 16 MB  [8192][1024]
    unsigned char* mask8 = (unsigned char*)(ws + (88u << 20));   // 8 KB

    cast_x_kernel<<<4096, 256, 0, stream>>>(x, xb);
    transpose_w_kernel<<<dim3(16, 16, 4), 256, 0, stream>>>(Wq, Wk, Wv, Wo, Wt);
    mask_kernel<<<32, 256, 0, stream>>>(vm, mask8);

    gemm_bt<0><<<512, 256, 0, stream>>>(xb, Wt + 0 * 1048576, nullptr, nullptr, qb, nullptr);
    gemm_bt<0><<<512, 256, 0, stream>>>(xb, Wt + 1 * 1048576, nullptr, nullptr, kb, nullptr);
    gemm_bt<0><<<512, 256, 0, stream>>>(xb, Wt + 2 * 1048576, nullptr, nullptr, vb, nullptr);

    attn_kernel<<<1024, 256, 0, stream>>>(qb, kb, vb, ctx);

    gemm_bt<1><<<512, 256, 0, stream>>>(ctx, Wt + 3 * 1048576, bo, mask8, nullptr, (float*)d_out);
}

// Round 2
// 241.314 us; speedup vs baseline: 1.5254x; 1.5254x over previous
//
#include <hip/hip_runtime.h>

// Causal MHA with variable-length masking, bf16 MFMA pipeline.
// B=4 S=2048 D=1024 H=16 HD=64. Output f32 [B,S,D].
// R1: V produced pre-transposed ([B,H,HD,S]) by operand-swapped GEMM (kills the
//     8-way LDS transpose conflict), causal-paired attention blocks (qt, 15-qt)
//     for perfect balance (34 tiles/block, 512 blocks = 2/CU), setprio on MFMA.

typedef __attribute__((ext_vector_type(8))) short bf16x8;
typedef __attribute__((ext_vector_type(4))) float f32x4;

static __device__ __forceinline__ short f2bf(float f) {
    union { float f; unsigned u; } x; x.f = f;
    unsigned r = (x.u + 0x7FFFu + ((x.u >> 16) & 1u)) >> 16;   // RNE
    return (short)r;
}

constexpr int Bc = 4, Sc = 2048, Dc = 1024, Hc = 16, HDc = 64;
constexpr int LDK = 72;                  // padded LDS leading dim (bf16 elems)

// ---------------- prep kernels ----------------

__global__ void cast_x_kernel(const float* __restrict__ x, short* __restrict__ xb) {
    int i = blockIdx.x * blockDim.x + threadIdx.x;   // 1M threads, 8 elems each
    const float4* xin = (const float4*)x;
    float4 a = xin[i * 2 + 0];
    float4 b = xin[i * 2 + 1];
    bf16x8 o;
    o[0] = f2bf(a.x); o[1] = f2bf(a.y); o[2] = f2bf(a.z); o[3] = f2bf(a.w);
    o[4] = f2bf(b.x); o[5] = f2bf(b.y); o[6] = f2bf(b.z); o[7] = f2bf(b.w);
    *(bf16x8*)&xb[(size_t)i * 8] = o;
}

// W [k][n] f32 -> Wt [n][k] bf16 (per matrix), 64x64 tiles via LDS
__global__ void transpose_w_kernel(const float* __restrict__ W0, const float* __restrict__ W1,
                                   const float* __restrict__ W2, const float* __restrict__ W3,
                                   short* __restrict__ Wt) {
    __shared__ float tile[64][65];
    const float* W = blockIdx.z == 0 ? W0 : blockIdx.z == 1 ? W1 : blockIdx.z == 2 ? W2 : W3;
    short* out = Wt + (size_t)blockIdx.z * Dc * Dc;
    int k0 = blockIdx.y * 64, n0 = blockIdx.x * 64;
    int t = threadIdx.x;
#pragma unroll
    for (int i = 0; i < 4; i++) {
        int c = t + i * 256; int r = c >> 4, cc = (c & 15) * 4;
        float4 v = *(const float4*)&W[(size_t)(k0 + r) * Dc + n0 + cc];
        tile[r][cc + 0] = v.x; tile[r][cc + 1] = v.y;
        tile[r][cc + 2] = v.z; tile[r][cc + 3] = v.w;
    }
    __syncthreads();
#pragma unroll
    for (int i = 0; i < 2; i++) {
        int c = t + i * 256; int nn = c >> 3, kc = (c & 7) * 8;
        bf16x8 o;
#pragma unroll
        for (int j = 0; j < 8; j++) o[j] = f2bf(tile[kc + j][nn]);
        *(bf16x8*)&out[(size_t)(n0 + nn) * Dc + k0 + kc] = o;
    }
}

// valid_mask (bool8 / int32 / float32 on the wire) -> u8. Probe word 0: batch 0 row 0 is valid.
__global__ void mask_kernel(const unsigned int* __restrict__ m, unsigned char* __restrict__ mask8) {
    int i = blockIdx.x * blockDim.x + threadIdx.x;   // 8192 threads
    unsigned w0 = m[0];
    unsigned char v;
    if (w0 == 1u)                 v = (unsigned char)(m[i] != 0);          // int32
    else if (w0 == 0x01010101u)   v = ((const unsigned char*)m)[i];        // bool (1B)
    else                          v = (((const float*)m)[i] != 0.0f);      // float32
    mask8[i] = v ? 1 : 0;
}

// ---------------- GEMM: D[m][n] = sum_k A[m][k] * Bt[n][k], K=1024 ----------------
// MODE 0: A=x[8192,K], Bt=W[1024,K]; store bf16 [B,H,S,HD]   (Q,K projections)
// MODE 1: A=ctx[8192,K], Bt=Wo[1024,K]; +bias, row-mask, f32 out [8192,1024]
// MODE 2: A=Wv[1024,K], Bt=x[8192,K]; D = V^T; store bf16 [B,H,HD,S] coalesced
template <int MODE>
__global__ __launch_bounds__(256, 2) void gemm_bt(
    const short* __restrict__ A, const short* __restrict__ Bt,
    const float* __restrict__ bias, const unsigned char* __restrict__ mask,
    short* __restrict__ outb, float* __restrict__ outf) {
    constexpr int K = 1024;
    __shared__ short la[128 * LDK];
    __shared__ short lb[128 * LDK];
    int bid = blockIdx.x;
    int tm, tn;
    if (MODE == 2) { tm = bid & 7; tn = bid >> 3; }   // M=1024 (8 tiles), N=8192 (64 tiles)
    else           { tm = bid >> 3; tn = bid & 7; }   // M=8192, N=1024
    int brow = tm * 128, bcol = tn * 128;
    int t = threadIdx.x;
    int w = t >> 6, l = t & 63;
    int wr = w >> 1, wc = w & 1;                   // wave quadrant (64x64)
    int lr = l & 15, lg = l >> 4;

    f32x4 zero4 = {0.f, 0.f, 0.f, 0.f};
    f32x4 acc[4][4];
#pragma unroll
    for (int mi = 0; mi < 4; mi++)
#pragma unroll
        for (int ni = 0; ni < 4; ni++) acc[mi][ni] = zero4;

    bf16x8 ra[4], rb[4];
#pragma unroll
    for (int i = 0; i < 4; i++) {                  // preload K-step 0
        int c = t + i * 256; int r = c >> 3, cc = (c & 7) * 8;
        ra[i] = *(const bf16x8*)&A [(size_t)(brow + r) * K + cc];
        rb[i] = *(const bf16x8*)&Bt[(size_t)(bcol + r) * K + cc];
    }

    for (int kt = 0; kt < K; kt += 64) {
        __syncthreads();                           // prev compute done
#pragma unroll
        for (int i = 0; i < 4; i++) {
            int c = t + i * 256; int r = c >> 3, cc = (c & 7) * 8;
            *(bf16x8*)&la[r * LDK + cc] = ra[i];
            *(bf16x8*)&lb[r * LDK + cc] = rb[i];
        }
        __syncthreads();
        if (kt + 64 < K) {                         // prefetch next K-step into regs
#pragma unroll
            for (int i = 0; i < 4; i++) {
                int c = t + i * 256; int r = c >> 3, cc = (c & 7) * 8;
                ra[i] = *(const bf16x8*)&A [(size_t)(brow + r) * K + kt + 64 + cc];
                rb[i] = *(const bf16x8*)&Bt[(size_t)(bcol + r) * K + kt + 64 + cc];
            }
        }
        __builtin_amdgcn_s_setprio(1);
#pragma unroll
        for (int kk = 0; kk < 2; kk++) {
            bf16x8 af[4], bfr[4];
#pragma unroll
            for (int mi = 0; mi < 4; mi++)
                af[mi] = *(const bf16x8*)&la[(wr * 64 + mi * 16 + lr) * LDK + kk * 32 + lg * 8];
#pragma unroll
            for (int ni = 0; ni < 4; ni++)
                bfr[ni] = *(const bf16x8*)&lb[(wc * 64 + ni * 16 + lr) * LDK + kk * 32 + lg * 8];
#pragma unroll
            for (int mi = 0; mi < 4; mi++)
#pragma unroll
                for (int ni = 0; ni < 4; ni++)
                    acc[mi][ni] = __builtin_amdgcn_mfma_f32_16x16x32_bf16(
                        af[mi], bfr[ni], acc[mi][ni], 0, 0, 0);
        }
        __builtin_amdgcn_s_setprio(0);
    }

    // D layout: row = lg*4 + r, col = lr  (verified m89/m91)
#pragma unroll
    for (int mi = 0; mi < 4; mi++)
#pragma unroll
        for (int ni = 0; ni < 4; ni++)
#pragma unroll
            for (int r = 0; r < 4; r++) {
                int m = brow + wr * 64 + mi * 16 + lg * 4 + r;
                int n = bcol + wc * 64 + ni * 16 + lr;
                float v = acc[mi][ni][r];
                if (MODE == 0) {
                    int b = m >> 11, s = m & 2047, h = n >> 6, hd = n & 63;
                    outb[((size_t)(b * Hc + h) * Sc + s) * HDc + hd] = f2bf(v);
                } else if (MODE == 2) {
                    int h = m >> 6, hd = m & 63, b = n >> 11, s = n & 2047;
                    outb[((size_t)((b * Hc + h) * HDc + hd)) * Sc + s] = f2bf(v);
                } else {
                    v += bias[n];
                    if (!mask[m]) v = 0.f;
                    outf[(size_t)m * Dc + n] = v;
                }
            }
}

// ---------------- flash attention (pure causal; mask handled in Wo epilogue) ----------------
// 512 blocks: bh (64) x pair p (8). Each block runs q-tiles p and 15-p sequentially
// -> exactly 34 K-tiles of work per block. 4 waves x 32 q-rows. KBLK=64.
// V comes in pre-transposed [B,H,HD,S] so staging is conflict-free b128 copies.
__global__ __launch_bounds__(256, 2) void attn_kernel(
    const short* __restrict__ Q, const short* __restrict__ Kp,
    const short* __restrict__ Vt, short* __restrict__ ctx) {
    __shared__ short lk[64 * LDK];                 // K tile [key][hd]
    __shared__ short lvt[64 * LDK];                // V^T tile [hd][key]
    __shared__ short lp[4][32 * LDK];              // per-wave P [qrow][key]
    int bid = blockIdx.x;
    int p = bid & 7, bh = bid >> 3;
    const short* qp  = Q  + (size_t)bh * Sc * HDc;
    const short* kp  = Kp + (size_t)bh * Sc * HDc;
    const short* vpt = Vt + (size_t)bh * HDc * Sc;
    int t = threadIdx.x, w = t >> 6, l = t & 63;
    int lr = l & 15, lg = l >> 4;
    int b = bh >> 4, h = bh & 15;

    for (int ph = 0; ph < 2; ph++) {
        int qt = ph == 0 ? p : 15 - p;
        int qbase = qt * 128;
        int wq = qbase + w * 32;                   // this wave's q rows [wq, wq+32)

        bf16x8 qf[2][2];
#pragma unroll
        for (int mi = 0; mi < 2; mi++)
#pragma unroll
            for (int kk = 0; kk < 2; kk++)
                qf[mi][kk] = *(const bf16x8*)&qp[(size_t)(wq + mi * 16 + lr) * HDc + kk * 32 + lg * 8];

        f32x4 zero4 = {0.f, 0.f, 0.f, 0.f};
        f32x4 o[2][4];
        float mrow[2][4], lrow[2][4];
#pragma unroll
        for (int mi = 0; mi < 2; mi++) {
#pragma unroll
            for (int ni = 0; ni < 4; ni++) o[mi][ni] = zero4;
#pragma unroll
            for (int r = 0; r < 4; r++) { mrow[mi][r] = -1e30f; lrow[mi][r] = 0.f; }
        }

        int nt = qbase / 64 + 2;                   // causal tile count for this q-tile
        bf16x8 rk[2], rv[2];
#pragma unroll
        for (int i = 0; i < 2; i++) {              // preload tile 0
            int c = t + i * 256; int r = c >> 3, cc = (c & 7) * 8;
            rk[i] = *(const bf16x8*)&kp [(size_t)r * HDc + cc];
            rv[i] = *(const bf16x8*)&vpt[(size_t)r * Sc + cc];         // r=hd row, cc=key
        }

        for (int tk = 0; tk < nt; tk++) {
            int k0 = tk * 64;
            __syncthreads();
#pragma unroll
            for (int i = 0; i < 2; i++) {
                int c = t + i * 256; int r = c >> 3, cc = (c & 7) * 8;
                *(bf16x8*)&lk [r * LDK + cc] = rk[i];
                *(bf16x8*)&lvt[r * LDK + cc] = rv[i];
            }
            __syncthreads();
            if (tk + 1 < nt) {
#pragma unroll
                for (int i = 0; i < 2; i++) {
                    int c = t + i * 256; int r = c >> 3, cc = (c & 7) * 8;
                    rk[i] = *(const bf16x8*)&kp [(size_t)(k0 + 64 + r) * HDc + cc];
                    rv[i] = *(const bf16x8*)&vpt[(size_t)r * Sc + k0 + 64 + cc];
                }
            }
            if (k0 <= wq + 31) {                   // wave-uniform causal skip
                // S = Q K^T
                f32x4 s[2][4];
#pragma unroll
                for (int mi = 0; mi < 2; mi++)
#pragma unroll
                    for (int ni = 0; ni < 4; ni++) s[mi][ni] = zero4;
                bf16x8 kf[4][2];
#pragma unroll
                for (int ni = 0; ni < 4; ni++)
#pragma unroll
                    for (int kk = 0; kk < 2; kk++)
                        kf[ni][kk] = *(const bf16x8*)&lk[(ni * 16 + lr) * LDK + kk * 32 + lg * 8];
                __builtin_amdgcn_s_setprio(1);
#pragma unroll
                for (int mi = 0; mi < 2; mi++)
#pragma unroll
                    for (int ni = 0; ni < 4; ni++)
#pragma unroll
                        for (int kk = 0; kk < 2; kk++)
                            s[mi][ni] = __builtin_amdgcn_mfma_f32_16x16x32_bf16(
                                qf[mi][kk], kf[ni][kk], s[mi][ni], 0, 0, 0);
                __builtin_amdgcn_s_setprio(0);
                // online softmax: row = wq + mi*16 + lg*4 + r, col/key = k0 + ni*16 + lr
                float corr[2][4];
#pragma unroll
                for (int mi = 0; mi < 2; mi++)
#pragma unroll
                    for (int r = 0; r < 4; r++) {
                        int qrow = wq + mi * 16 + lg * 4 + r;
                        float mx = -1e30f;
#pragma unroll
                        for (int ni = 0; ni < 4; ni++) {
                            int key = k0 + ni * 16 + lr;
                            float sv = s[mi][ni][r] * 0.125f;    // 1/sqrt(64)
                            if (key > qrow) sv = -1e30f;
                            s[mi][ni][r] = sv;
                            mx = fmaxf(mx, sv);
                        }
                        for (int d = 1; d < 16; d <<= 1) mx = fmaxf(mx, __shfl_xor(mx, d, 64));
                        float mnew = fmaxf(mrow[mi][r], mx);
                        corr[mi][r] = __expf(mrow[mi][r] - mnew);
                        mrow[mi][r] = mnew;
                        float sum = 0.f;
#pragma unroll
                        for (int ni = 0; ni < 4; ni++) {
                            float pv = __expf(s[mi][ni][r] - mnew);
                            s[mi][ni][r] = pv;
                            sum += pv;
                        }
                        for (int d = 1; d < 16; d <<= 1) sum += __shfl_xor(sum, d, 64);
                        lrow[mi][r] = lrow[mi][r] * corr[mi][r] + sum;
                    }
                // P -> LDS (bf16), rescale O
#pragma unroll
                for (int mi = 0; mi < 2; mi++)
#pragma unroll
                    for (int ni = 0; ni < 4; ni++)
#pragma unroll
                        for (int r = 0; r < 4; r++)
                            lp[w][(mi * 16 + lg * 4 + r) * LDK + ni * 16 + lr] = f2bf(s[mi][ni][r]);
#pragma unroll
                for (int mi = 0; mi < 2; mi++)
#pragma unroll
                    for (int ni = 0; ni < 4; ni++)
#pragma unroll
                        for (int r = 0; r < 4; r++) o[mi][ni][r] *= corr[mi][r];
                // O += P V
                bf16x8 pa[2][2], vbf[4][2];
#pragma unroll
                for (int mi = 0; mi < 2; mi++)
#pragma unroll
                    for (int kk = 0; kk < 2; kk++)
                        pa[mi][kk] = *(const bf16x8*)&lp[w][(mi * 16 + lr) * LDK + kk * 32 + lg * 8];
#pragma unroll
                for (int ni = 0; ni < 4; ni++)
#pragma unroll
                    for (int kk = 0; kk < 2; kk++)
                        vbf[ni][kk] = *(const bf16x8*)&lvt[(ni * 16 + lr) * LDK + kk * 32 + lg * 8];
                __builtin_amdgcn_s_setprio(1);
#pragma unroll
                for (int mi = 0; mi < 2; mi++)
#pragma unroll
                    for (int ni = 0; ni < 4; ni++)
#pragma unroll
                        for (int kk = 0; kk < 2; kk++)
                            o[mi][ni] = __builtin_amdgcn_mfma_f32_16x16x32_bf16(
                                pa[mi][kk], vbf[ni][kk], o[mi][ni], 0, 0, 0);
                __builtin_amdgcn_s_setprio(0);
            }
        }
        // epilogue: ctx[b*S+s][h*64+hd] bf16
#pragma unroll
        for (int mi = 0; mi < 2; mi++)
#pragma unroll
            for (int ni = 0; ni < 4; ni++)
#pragma unroll
                for (int r = 0; r < 4; r++) {
                    int srow = wq + mi * 16 + lg * 4 + r;
                    float v = o[mi][ni][r] / lrow[mi][r];
                    ctx[(size_t)(b * Sc + srow) * Dc + h * 64 + ni * 16 + lr] = f2bf(v);
                }
    }
}

// ---------------- launch ----------------

extern "C" void kernel_launch(void* const* d_in, const int* in_sizes, int n_in,
                              void* d_out, int out_size, void* d_ws, size_t ws_size,
                              hipStream_t stream) {
    (void)in_sizes; (void)n_in; (void)out_size; (void)ws_size;
    const float* x  = (const float*)d_in[0];
    const float* Wq = (const float*)d_in[1];
    const float* Wk = (const float*)d_in[2];
    const float* Wv = (const float*)d_in[3];
    const float* Wo = (const float*)d_in[4];
    const float* bo = (const float*)d_in[5];
    const unsigned int* vm = (const unsigned int*)d_in[6];

    char* ws = (char*)d_ws;
    short* xb  = (short*)(ws);                       // 16 MB  x bf16 [8192][1024]
    short* Wt  = (short*)(ws + (16u << 20));         //  8 MB  Wt bf16 [4][1024][1024]
    short* qb  = (short*)(ws + (24u << 20));         // 16 MB  [B,H,S,HD]
    short* kb  = (short*)(ws + (40u << 20));         // 16 MB  [B,H,S,HD]
    short* vt  = (short*)(ws + (56u << 20));         // 16 MB  [B,H,HD,S]  (V^T)
    short* ctx = (short*)(ws + (72u << 20));         // 16 MB  [8192][1024]
    unsigned char* mask8 = (unsigned char*)(ws + (88u << 20));   // 8 KB

    cast_x_kernel<<<4096, 256, 0, stream>>>(x, xb);
    transpose_w_kernel<<<dim3(16, 16, 4), 256, 0, stream>>>(Wq, Wk, Wv, Wo, Wt);
    mask_kernel<<<32, 256, 0, stream>>>(vm, mask8);

    gemm_bt<0><<<512, 256, 0, stream>>>(xb, Wt + 0 * 1048576, nullptr, nullptr, qb, nullptr);
    gemm_bt<0><<<512, 256, 0, stream>>>(xb, Wt + 1 * 1048576, nullptr, nullptr, kb, nullptr);
    // V^T = Wv^T (as A) x x (as B): D[m=out_dim][n=token], stored [B,H,HD,S]
    gemm_bt<2><<<512, 256, 0, stream>>>(Wt + 2 * 1048576, xb, nullptr, nullptr, vt, nullptr);

    attn_kernel<<<512, 256, 0, stream>>>(qb, kb, vt, ctx);

    gemm_bt<1><<<512, 256, 0, stream>>>(ctx, Wt + 3 * 1048576, bo, mask8, nullptr, (float*)d_out);
}

// Round 4
// 209.632 us; speedup vs baseline: 1.7559x; 1.1511x over previous
//
#include <hip/hip_runtime.h>

// Causal MHA, bf16 MFMA pipeline. B=4 S=2048 D=1024 H=16 HD=64. Out f32 [B,S,D].
// R3: fix R2's NaN — permlane32_swap via builtin (the inline-asm "+v","+v" pair
//     could alias both operands to ONE register when fed the same value, making
//     pair_sum return 2*partner-sum -> lrow=0 -> inf -> NaN downstream).
//     GEMMs: m97-style global_load_lds staging. Attention: swapped-operand 32x32
//     MFMA, fully in-register softmax (cvt_pk_bf16 + permlane32_swap).

typedef __attribute__((ext_vector_type(8))) short bf16x8;
typedef __attribute__((ext_vector_type(4))) float f32x4;
typedef __attribute__((ext_vector_type(16))) float f32x16;
typedef __attribute__((ext_vector_type(2))) unsigned uint2v;

static __device__ __forceinline__ short f2bf(float f) {
    union { float f; unsigned u; } x; x.f = f;
    unsigned r = (x.u + 0x7FFFu + ((x.u >> 16) & 1u)) >> 16;   // RNE
    return (short)r;
}

__device__ __forceinline__ void gload_lds16(const void* g, void* lds) {
    __builtin_amdgcn_global_load_lds(
        (const __attribute__((address_space(1))) unsigned int*)g,
        (__attribute__((address_space(3))) unsigned int*)lds, 16, 0, 0);
}

__device__ __forceinline__ unsigned cvt_pk_bf16(float lo, float hi) {
    unsigned r;
    asm volatile("v_cvt_pk_bf16_f32 %0, %1, %2" : "=v"(r) : "v"(lo), "v"(hi));
    return r;
}

// new_a[0:31]=old_a[0:31], new_a[32:63]=old_b[0:31],
// new_b[0:31]=old_a[32:63], new_b[32:63]=old_b[32:63]
__device__ __forceinline__ float pair_max(float x) {       // max with lane^32
    union { float f; unsigned u; } c; c.f = x;
    uint2v r = __builtin_amdgcn_permlane32_swap(c.u, c.u, false, false);
    union { unsigned u; float f; } a, b; a.u = r[0]; b.u = r[1];
    return fmaxf(a.f, b.f);
}

__device__ __forceinline__ float pair_sum(float x) {       // sum with lane^32
    union { float f; unsigned u; } c; c.f = x;
    uint2v r = __builtin_amdgcn_permlane32_swap(c.u, c.u, false, false);
    union { unsigned u; float f; } a, b; a.u = r[0]; b.u = r[1];
    return a.f + b.f;
}

constexpr int Bc = 4, Sc = 2048, Dc = 1024, Hc = 16, HDc = 64;

// ---------------- prep kernels ----------------

__global__ void cast_x_kernel(const float* __restrict__ x, short* __restrict__ xb) {
    int i = blockIdx.x * blockDim.x + threadIdx.x;
    const float4* xin = (const float4*)x;
    float4 a = xin[i * 2 + 0];
    float4 b = xin[i * 2 + 1];
    bf16x8 o;
    o[0] = f2bf(a.x); o[1] = f2bf(a.y); o[2] = f2bf(a.z); o[3] = f2bf(a.w);
    o[4] = f2bf(b.x); o[5] = f2bf(b.y); o[6] = f2bf(b.z); o[7] = f2bf(b.w);
    *(bf16x8*)&xb[(size_t)i * 8] = o;
}

__global__ void transpose_w_kernel(const float* __restrict__ W0, const float* __restrict__ W1,
                                   const float* __restrict__ W2, const float* __restrict__ W3,
                                   short* __restrict__ Wt) {
    __shared__ float tile[64][65];
    const float* W = blockIdx.z == 0 ? W0 : blockIdx.z == 1 ? W1 : blockIdx.z == 2 ? W2 : W3;
    short* out = Wt + (size_t)blockIdx.z * Dc * Dc;
    int k0 = blockIdx.y * 64, n0 = blockIdx.x * 64;
    int t = threadIdx.x;
#pragma unroll
    for (int i = 0; i < 4; i++) {
        int c = t + i * 256; int r = c >> 4, cc = (c & 15) * 4;
        float4 v = *(const float4*)&W[(size_t)(k0 + r) * Dc + n0 + cc];
        tile[r][cc + 0] = v.x; tile[r][cc + 1] = v.y;
        tile[r][cc + 2] = v.z; tile[r][cc + 3] = v.w;
    }
    __syncthreads();
#pragma unroll
    for (int i = 0; i < 2; i++) {
        int c = t + i * 256; int nn = c >> 3, kc = (c & 7) * 8;
        bf16x8 o;
#pragma unroll
        for (int j = 0; j < 8; j++) o[j] = f2bf(tile[kc + j][nn]);
        *(bf16x8*)&out[(size_t)(n0 + nn) * Dc + k0 + kc] = o;
    }
}

__global__ void mask_kernel(const unsigned int* __restrict__ m, unsigned char* __restrict__ mask8) {
    int i = blockIdx.x * blockDim.x + threadIdx.x;
    unsigned w0 = m[0];
    unsigned char v;
    if (w0 == 1u)                 v = (unsigned char)(m[i] != 0);
    else if (w0 == 0x01010101u)   v = ((const unsigned char*)m)[i];
    else                          v = (((const float*)m)[i] != 0.0f);
    mask8[i] = v ? 1 : 0;
}

// ---------------- GEMM: D[m][n] = sum_k A[m][k] * Bt[n][k], K=1024 ----------------
// m97 structure: global_load_lds dwordx4 staging into linear [128][64] LDS tiles.
// MODE 0: store bf16 [B,H,S,HD].  MODE 1: +bias,row-mask, f32 out.  MODE 2: V^T [B,H,HD,S].
template <int MODE>
__global__ __launch_bounds__(256, 2) void gemm_bt(
    const short* __restrict__ A, const short* __restrict__ Bt,
    const float* __restrict__ bias, const unsigned char* __restrict__ mask,
    short* __restrict__ outb, float* __restrict__ outf) {
    constexpr int K = 1024;
    __shared__ __attribute__((aligned(16))) short la[128 * 64];
    __shared__ __attribute__((aligned(16))) short lb[128 * 64];
    int bid = blockIdx.x;
    int tm, tn;
    if (MODE == 2) { tm = bid & 7; tn = bid >> 3; }
    else           { tm = bid >> 3; tn = bid & 7; }
    int brow = tm * 128, bcol = tn * 128;
    int t = threadIdx.x;
    int w = t >> 6, l = t & 63;
    int wr = w >> 1, wc = w & 1;
    int lr = l & 15, lg = l >> 4;

    f32x4 zero4 = {0.f, 0.f, 0.f, 0.f};
    f32x4 acc[4][4];
#pragma unroll
    for (int mi = 0; mi < 4; mi++)
#pragma unroll
        for (int ni = 0; ni < 4; ni++) acc[mi][ni] = zero4;

    int lrow8 = l >> 3, lcol = (l & 7) * 8;        // staging: lane covers 16B

    for (int kt = 0; kt < K; kt += 64) {
        __syncthreads();                           // prev compute done
#pragma unroll
        for (int i = 0; i < 4; i++) {
            int seg = w * 4 + i;                   // 0..15, 8 rows each
            int row = seg * 8 + lrow8;
            gload_lds16(&A [(size_t)(brow + row) * K + kt + lcol], &la[seg * 512]);
            gload_lds16(&Bt[(size_t)(bcol + row) * K + kt + lcol], &lb[seg * 512]);
        }
        __syncthreads();                           // drains vmcnt(0)
        __builtin_amdgcn_s_setprio(1);
#pragma unroll
        for (int kk = 0; kk < 2; kk++) {
            bf16x8 af[4], bfr[4];
#pragma unroll
            for (int mi = 0; mi < 4; mi++)
                af[mi] = *(const bf16x8*)&la[(wr * 64 + mi * 16 + lr) * 64 + kk * 32 + lg * 8];
#pragma unroll
            for (int ni = 0; ni < 4; ni++)
                bfr[ni] = *(const bf16x8*)&lb[(wc * 64 + ni * 16 + lr) * 64 + kk * 32 + lg * 8];
#pragma unroll
            for (int mi = 0; mi < 4; mi++)
#pragma unroll
                for (int ni = 0; ni < 4; ni++)
                    acc[mi][ni] = __builtin_amdgcn_mfma_f32_16x16x32_bf16(
                        af[mi], bfr[ni], acc[mi][ni], 0, 0, 0);
        }
        __builtin_amdgcn_s_setprio(0);
    }

#pragma unroll
    for (int mi = 0; mi < 4; mi++)
#pragma unroll
        for (int ni = 0; ni < 4; ni++)
#pragma unroll
            for (int r = 0; r < 4; r++) {
                int m = brow + wr * 64 + mi * 16 + lg * 4 + r;
                int n = bcol + wc * 64 + ni * 16 + lr;
                float v = acc[mi][ni][r];
                if (MODE == 0) {
                    int b = m >> 11, s = m & 2047, h = n >> 6, hd = n & 63;
                    outb[((size_t)(b * Hc + h) * Sc + s) * HDc + hd] = f2bf(v);
                } else if (MODE == 2) {
                    int h = m >> 6, hd = m & 63, b = n >> 11, s = n & 2047;
                    outb[((size_t)((b * Hc + h) * HDc + hd)) * Sc + s] = f2bf(v);
                } else {
                    v += bias[n];
                    if (!mask[m]) v = 0.f;
                    outf[(size_t)m * Dc + n] = v;
                }
            }
}

// ---------------- flash attention, swapped-operand 32x32, in-register softmax ------------
// 512 blocks = 64 bh x 8 pairs; block runs q-tiles p and 15-p (34 K-tiles total).
// 4 waves x 32 q-rows. Per lane: query = lane&31 (hi = lane>>5 holds key-half).
// K LDS chunks: ((kb2*4+m16)*2+hi)*32+key ; V^T chunks: ((hd2*4+ks)*2+hi)*32+hd32.
__global__ __launch_bounds__(256, 2) void attn_kernel(
    const short* __restrict__ Q, const short* __restrict__ Kp,
    const short* __restrict__ Vt, short* __restrict__ ctx) {
    __shared__ __attribute__((aligned(16))) short smem[9216];  // 18KB; stage K[0:4096) V[4096:8192); epilogue 4x2304
    short* lk  = smem;
    short* lvt = smem + 4096;
    int bid = blockIdx.x;
    int p = bid & 7, bh = bid >> 3;
    const short* qp  = Q  + (size_t)bh * Sc * HDc;
    const short* kp  = Kp + (size_t)bh * Sc * HDc;
    const short* vpt = Vt + (size_t)bh * HDc * Sc;
    int t = threadIdx.x, w = t >> 6, l = t & 63;
    int la31 = l & 31, hi = l >> 5, hi4 = hi * 4;
    int b = bh >> 4, h = bh & 15;
    const float cexp = 0.125f * 1.44269504088896f;   // (1/sqrt(64)) * log2(e)

    // staging chunk ids for this thread
    int c0 = t, c1 = t + 256;
    // K chunk decode: key=c&31, chi=(c>>5)&1, cm16=(c>>6)&3, ckb2=(c>>8)&1
#define KSRC(c, k0) (&kp[(size_t)((k0) + (((c) >> 8) & 1) * 32 + ((c) & 31)) * HDc + (((c) >> 6) & 3) * 16 + (((c) >> 5) & 1) * 8])
#define VSRC(c, k0) (&vpt[(size_t)((((c) >> 8) & 1) * 32 + ((c) & 31)) * Sc + (k0) + (((c) >> 6) & 3) * 16 + (((c) >> 5) & 1) * 8])

    for (int ph = 0; ph < 2; ph++) {
        int qt = ph == 0 ? p : 15 - p;
        int qbase = qt * 128;
        int wq = qbase + w * 32;
        int qla = wq + la31;

        bf16x8 qf[4];
#pragma unroll
        for (int m16 = 0; m16 < 4; m16++)
            qf[m16] = *(const bf16x8*)&qp[(size_t)qla * HDc + m16 * 16 + hi * 8];

        f32x16 o0, o1;
#pragma unroll
        for (int r = 0; r < 16; r++) { o0[r] = 0.f; o1[r] = 0.f; }
        float mrow = -3e38f, lrow = 0.f;

        int nt = qbase / 64 + 2;
        bf16x8 rk0 = *(const bf16x8*)KSRC(c0, 0), rk1 = *(const bf16x8*)KSRC(c1, 0);
        bf16x8 rv0 = *(const bf16x8*)VSRC(c0, 0), rv1 = *(const bf16x8*)VSRC(c1, 0);

        for (int tk = 0; tk < nt; tk++) {
            int k0 = tk * 64;
            __syncthreads();
            *(bf16x8*)&lk [c0 * 8] = rk0;  *(bf16x8*)&lk [c1 * 8] = rk1;
            *(bf16x8*)&lvt[c0 * 8] = rv0;  *(bf16x8*)&lvt[c1 * 8] = rv1;
            __syncthreads();
            if (tk + 1 < nt) {
                rk0 = *(const bf16x8*)KSRC(c0, k0 + 64); rk1 = *(const bf16x8*)KSRC(c1, k0 + 64);
                rv0 = *(const bf16x8*)VSRC(c0, k0 + 64); rv1 = *(const bf16x8*)VSRC(c1, k0 + 64);
            }
            if (k0 <= wq + 31) {
                // ---- S^T = K Q^T : D[key][query], lane owns query la31, key-half hi
                f32x16 s0, s1;
#pragma unroll
                for (int r = 0; r < 16; r++) { s0[r] = 0.f; s1[r] = 0.f; }
                __builtin_amdgcn_s_setprio(1);
#pragma unroll
                for (int m16 = 0; m16 < 4; m16++) {
                    bf16x8 kf0 = *(const bf16x8*)&lk[((m16 * 2 + hi) * 32 + la31) * 8];
                    bf16x8 kf1 = *(const bf16x8*)&lk[(((4 + m16) * 2 + hi) * 32 + la31) * 8];
                    s0 = __builtin_amdgcn_mfma_f32_32x32x16_bf16(kf0, qf[m16], s0, 0, 0, 0);
                    s1 = __builtin_amdgcn_mfma_f32_32x32x16_bf16(kf1, qf[m16], s1, 0, 0, 0);
                }
                __builtin_amdgcn_s_setprio(0);

                // ---- online softmax, fully in-register (keys of lane: kb2*32+(r&3)+8*(r>>2)+4*hi)
                float mx = -3e38f;
                if (k0 + 64 > wq) {                         // diagonal tiles: apply causal mask
#pragma unroll
                    for (int r = 0; r < 16; r++) {
                        int key = k0 + ((r & 3) + 8 * (r >> 2)) + hi4;
                        float a0 = (key      <= qla) ? s0[r] : -3e38f; s0[r] = a0;
                        float a1 = (key + 32 <= qla) ? s1[r] : -3e38f; s1[r] = a1;
                        mx = fmaxf(mx, fmaxf(a0, a1));
                    }
                } else {
#pragma unroll
                    for (int r = 0; r < 16; r++) mx = fmaxf(mx, fmaxf(s0[r], s1[r]));
                }
                mx = pair_max(mx);
                float mnew = fmaxf(mrow, mx);
                float mc = mnew * cexp;
                float corr = exp2f(fmaf(mrow, cexp, -mc));
                mrow = mnew;
                float sum = 0.f;
#pragma unroll
                for (int r = 0; r < 16; r++) {
                    float p0 = exp2f(fmaf(s0[r], cexp, -mc)); s0[r] = p0;
                    float p1 = exp2f(fmaf(s1[r], cexp, -mc)); s1[r] = p1;
                    sum += p0 + p1;
                }
                sum = pair_sum(sum);
                lrow = lrow * corr + sum;
#pragma unroll
                for (int r = 0; r < 16; r++) { o0[r] *= corr; o1[r] *= corr; }

                // ---- O^T += V^T P^T : pack P to bf16 B-operand via cvt_pk + permlane32_swap
                union U { unsigned u[4]; bf16x8 v; };
                __builtin_amdgcn_s_setprio(1);
#define PVSTEP(SP, KS, KS2) do {                                                   \
                    unsigned w0 = cvt_pk_bf16(SP[8*(KS2)+0], SP[8*(KS2)+1]);       \
                    unsigned w1 = cvt_pk_bf16(SP[8*(KS2)+2], SP[8*(KS2)+3]);       \
                    unsigned x0 = cvt_pk_bf16(SP[8*(KS2)+4], SP[8*(KS2)+5]);       \
                    unsigned x1 = cvt_pk_bf16(SP[8*(KS2)+6], SP[8*(KS2)+7]);       \
                    uint2v r0 = __builtin_amdgcn_permlane32_swap(w0, x0, false, false); \
                    uint2v r1 = __builtin_amdgcn_permlane32_swap(w1, x1, false, false); \
                    U pu; pu.u[0] = r0[0]; pu.u[1] = r1[0]; pu.u[2] = r0[1]; pu.u[3] = r1[1]; \
                    bf16x8 av0 = *(const bf16x8*)&lvt[(((KS) * 2 + hi) * 32 + la31) * 8];        \
                    bf16x8 av1 = *(const bf16x8*)&lvt[(((4 + (KS)) * 2 + hi) * 32 + la31) * 8];  \
                    o0 = __builtin_amdgcn_mfma_f32_32x32x16_bf16(av0, pu.v, o0, 0, 0, 0);        \
                    o1 = __builtin_amdgcn_mfma_f32_32x32x16_bf16(av1, pu.v, o1, 0, 0, 0);        \
                } while (0)
                PVSTEP(s0, 0, 0); PVSTEP(s0, 1, 1); PVSTEP(s1, 2, 0); PVSTEP(s1, 3, 1);
#undef PVSTEP
                __builtin_amdgcn_s_setprio(0);
            }
        }

        // ---- epilogue: O^T regs -> per-warp LDS transpose -> vectorized global store
        __syncthreads();                            // all warps done reading lk/lvt
        float rl = 1.0f / lrow;
        short* ep = &smem[w * 2304];                // [32 q][72] per warp
#pragma unroll
        for (int r = 0; r < 16; r++) {
            int hd = (r & 3) + 8 * (r >> 2) + hi4;
            ep[la31 * 72 + hd]      = f2bf(o0[r] * rl);
            ep[la31 * 72 + 32 + hd] = f2bf(o1[r] * rl);
        }
        asm volatile("s_waitcnt lgkmcnt(0)" ::: "memory");
        __builtin_amdgcn_sched_barrier(0);
        int erow = l >> 1, ecol = (l & 1) * 32;
        size_t gbase = ((size_t)(b * Sc + wq + erow)) * Dc + h * 64 + ecol;
#pragma unroll
        for (int i2 = 0; i2 < 4; i2++)
            *(bf16x8*)&ctx[gbase + i2 * 8] = *(const bf16x8*)&ep[erow * 72 + ecol + i2 * 8];
    }
#undef KSRC
#undef VSRC
}

// ---------------- launch ----------------

extern "C" void kernel_launch(void* const* d_in, const int* in_sizes, int n_in,
                              void* d_out, int out_size, void* d_ws, size_t ws_size,
                              hipStream_t stream) {
    (void)in_sizes; (void)n_in; (void)out_size; (void)ws_size;
    const float* x  = (const float*)d_in[0];
    const float* Wq = (const float*)d_in[1];
    const float* Wk = (const float*)d_in[2];
    const float* Wv = (const float*)d_in[3];
    const float* Wo = (const float*)d_in[4];
    const float* bo = (const float*)d_in[5];
    const unsigned int* vm = (const unsigned int*)d_in[6];

    char* ws = (char*)d_ws;
    short* xb  = (short*)(ws);                       // 16 MB  x bf16 [8192][1024]
    short* Wt  = (short*)(ws + (16u << 20));         //  8 MB  Wt bf16 [4][1024][1024]
    short* qb  = (short*)(ws + (24u << 20));         // 16 MB  [B,H,S,HD]
    short* kb  = (short*)(ws + (40u << 20));         // 16 MB  [B,H,S,HD]
    short* vt  = (short*)(ws + (56u << 20));         // 16 MB  [B,H,HD,S]  (V^T)
    short* ctx = (short*)(ws + (72u << 20));         // 16 MB  [8192][1024]
    unsigned char* mask8 = (unsigned char*)(ws + (88u << 20));   // 8 KB

    cast_x_kernel<<<4096, 256, 0, stream>>>(x, xb);
    transpose_w_kernel<<<dim3(16, 16, 4), 256, 0, stream>>>(Wq, Wk, Wv, Wo, Wt);
    mask_kernel<<<32, 256, 0, stream>>>(vm, mask8);

    gemm_bt<0><<<512, 256, 0, stream>>>(xb, Wt + 0 * 1048576, nullptr, nullptr, qb, nullptr);
    gemm_bt<0><<<512, 256, 0, stream>>>(xb, Wt + 1 * 1048576, nullptr, nullptr, kb, nullptr);
    gemm_bt<2><<<512, 256, 0, stream>>>(Wt + 2 * 1048576, xb, nullptr, nullptr, vt, nullptr);

    attn_kernel<<<512, 256, 0, stream>>>(qb, kb, vt, ctx);

    gemm_bt<1><<<512, 256, 0, stream>>>(ctx, Wt + 3 * 1048576, bo, mask8, nullptr, (float*)d_out);
}

// Round 5
// 204.248 us; speedup vs baseline: 1.8022x; 1.0264x over previous
//
#include <hip/hip_runtime.h>

// Causal MHA, bf16 MFMA pipeline. B=4 S=2048 D=1024 H=16 HD=64. Out f32 [B,S,D].
// R4: GEMMs double-buffered (issue gload_lds before compute, 1 barrier/K-step),
//     Q+K fused into one N=2048 GEMM, XCD swizzles everywhere; attention gets
//     LDS double-buffer (1 barrier/tile), T13 defer-max, incremental pointers.

typedef __attribute__((ext_vector_type(8))) short bf16x8;
typedef __attribute__((ext_vector_type(4))) float f32x4;
typedef __attribute__((ext_vector_type(16))) float f32x16;
typedef __attribute__((ext_vector_type(2))) unsigned uint2v;

static __device__ __forceinline__ short f2bf(float f) {
    union { float f; unsigned u; } x; x.f = f;
    unsigned r = (x.u + 0x7FFFu + ((x.u >> 16) & 1u)) >> 16;   // RNE
    return (short)r;
}

__device__ __forceinline__ void gload_lds16(const void* g, void* lds) {
    __builtin_amdgcn_global_load_lds(
        (const __attribute__((address_space(1))) unsigned int*)g,
        (__attribute__((address_space(3))) unsigned int*)lds, 16, 0, 0);
}

__device__ __forceinline__ unsigned cvt_pk_bf16(float lo, float hi) {
    unsigned r;
    asm volatile("v_cvt_pk_bf16_f32 %0, %1, %2" : "=v"(r) : "v"(lo), "v"(hi));
    return r;
}

__device__ __forceinline__ float pair_max(float x) {       // max with lane^32
    union { float f; unsigned u; } c; c.f = x;
    uint2v r = __builtin_amdgcn_permlane32_swap(c.u, c.u, false, false);
    union { unsigned u; float f; } a, b; a.u = r[0]; b.u = r[1];
    return fmaxf(a.f, b.f);
}

__device__ __forceinline__ float pair_sum(float x) {       // sum with lane^32
    union { float f; unsigned u; } c; c.f = x;
    uint2v r = __builtin_amdgcn_permlane32_swap(c.u, c.u, false, false);
    union { unsigned u; float f; } a, b; a.u = r[0]; b.u = r[1];
    return a.f + b.f;
}

constexpr int Bc = 4, Sc = 2048, Dc = 1024, Hc = 16, HDc = 64;

// ---------------- prep kernels ----------------

__global__ void cast_x_kernel(const float* __restrict__ x, short* __restrict__ xb) {
    int i = blockIdx.x * blockDim.x + threadIdx.x;
    const float4* xin = (const float4*)x;
    float4 a = xin[i * 2 + 0];
    float4 b = xin[i * 2 + 1];
    bf16x8 o;
    o[0] = f2bf(a.x); o[1] = f2bf(a.y); o[2] = f2bf(a.z); o[3] = f2bf(a.w);
    o[4] = f2bf(b.x); o[5] = f2bf(b.y); o[6] = f2bf(b.z); o[7] = f2bf(b.w);
    *(bf16x8*)&xb[(size_t)i * 8] = o;
}

__global__ void transpose_w_kernel(const float* __restrict__ W0, const float* __restrict__ W1,
                                   const float* __restrict__ W2, const float* __restrict__ W3,
                                   short* __restrict__ Wt) {
    __shared__ float tile[64][65];
    const float* W = blockIdx.z == 0 ? W0 : blockIdx.z == 1 ? W1 : blockIdx.z == 2 ? W2 : W3;
    short* out = Wt + (size_t)blockIdx.z * Dc * Dc;
    int k0 = blockIdx.y * 64, n0 = blockIdx.x * 64;
    int t = threadIdx.x;
#pragma unroll
    for (int i = 0; i < 4; i++) {
        int c = t + i * 256; int r = c >> 4, cc = (c & 15) * 4;
        float4 v = *(const float4*)&W[(size_t)(k0 + r) * Dc + n0 + cc];
        tile[r][cc + 0] = v.x; tile[r][cc + 1] = v.y;
        tile[r][cc + 2] = v.z; tile[r][cc + 3] = v.w;
    }
    __syncthreads();
#pragma unroll
    for (int i = 0; i < 2; i++) {
        int c = t + i * 256; int nn = c >> 3, kc = (c & 7) * 8;
        bf16x8 o;
#pragma unroll
        for (int j = 0; j < 8; j++) o[j] = f2bf(tile[kc + j][nn]);
        *(bf16x8*)&out[(size_t)(n0 + nn) * Dc + k0 + kc] = o;
    }
}

__global__ void mask_kernel(const unsigned int* __restrict__ m, unsigned char* __restrict__ mask8) {
    int i = blockIdx.x * blockDim.x + threadIdx.x;
    unsigned w0 = m[0];
    unsigned char v;
    if (w0 == 1u)                 v = (unsigned char)(m[i] != 0);
    else if (w0 == 0x01010101u)   v = ((const unsigned char*)m)[i];
    else                          v = (((const float*)m)[i] != 0.0f);
    mask8[i] = v ? 1 : 0;
}

// ---------------- GEMM: D[m][n] = sum_k A[m][k] * Bt[n][k], K=1024 ----------------
// Double-buffered global_load_lds staging, 1 barrier per K-step.
// MODE 0: fused Q+K (Bt rows 0..2047 = Wq|Wk), store bf16 [B,H,S,HD] to outb/outb2.
// MODE 1: +bias, row-mask, f32 out.   MODE 2: V^T, store bf16 [B,H,HD,S].
template <int MODE>
__global__ __launch_bounds__(256, 2) void gemm_bt(
    const short* __restrict__ A, const short* __restrict__ Bt,
    const float* __restrict__ bias, const unsigned char* __restrict__ mask,
    short* __restrict__ outb, short* __restrict__ outb2, float* __restrict__ outf) {
    constexpr int K = 1024;
    __shared__ __attribute__((aligned(16))) short la[2][128 * 64];
    __shared__ __attribute__((aligned(16))) short lb[2][128 * 64];
    int bid = blockIdx.x;
    int swz = (bid & 7) * (gridDim.x >> 3) + (bid >> 3);   // XCD-contiguous chunks
    int tm, tn;
    if (MODE == 0)      { tm = swz >> 4; tn = swz & 15; }  // 64 x 16 tiles (N=2048)
    else if (MODE == 2) { tm = swz & 7;  tn = swz >> 3; }  // 8 x 64
    else                { tm = swz >> 3; tn = swz & 7;  }  // 64 x 8
    int brow = tm * 128, bcol = tn * 128;
    int t = threadIdx.x;
    int w = t >> 6, l = t & 63;
    int wr = w >> 1, wc = w & 1;
    int lr = l & 15, lg = l >> 4;
    int lrow8 = l >> 3, lcol = (l & 7) * 8;

    f32x4 zero4 = {0.f, 0.f, 0.f, 0.f};
    f32x4 acc[4][4];
#pragma unroll
    for (int mi = 0; mi < 4; mi++)
#pragma unroll
        for (int ni = 0; ni < 4; ni++) acc[mi][ni] = zero4;

    auto stage = [&](int bufi, int kt) {
#pragma unroll
        for (int i = 0; i < 4; i++) {
            int seg = w * 4 + i;
            int row = seg * 8 + lrow8;
            gload_lds16(&A [(size_t)(brow + row) * K + kt + lcol], &la[bufi][seg * 512]);
            gload_lds16(&Bt[(size_t)(bcol + row) * K + kt + lcol], &lb[bufi][seg * 512]);
        }
    };

    stage(0, 0);
    __syncthreads();                               // buf0 ready
    int buf = 0;
    for (int kt = 0; kt < K; kt += 64) {
        if (kt + 64 < K) stage(buf ^ 1, kt + 64);  // async loads overlap compute
        __builtin_amdgcn_s_setprio(1);
#pragma unroll
        for (int kk = 0; kk < 2; kk++) {
            bf16x8 af[4], bfr[4];
#pragma unroll
            for (int mi = 0; mi < 4; mi++)
                af[mi] = *(const bf16x8*)&la[buf][(wr * 64 + mi * 16 + lr) * 64 + kk * 32 + lg * 8];
#pragma unroll
            for (int ni = 0; ni < 4; ni++)
                bfr[ni] = *(const bf16x8*)&lb[buf][(wc * 64 + ni * 16 + lr) * 64 + kk * 32 + lg * 8];
#pragma unroll
            for (int mi = 0; mi < 4; mi++)
#pragma unroll
                for (int ni = 0; ni < 4; ni++)
                    acc[mi][ni] = __builtin_amdgcn_mfma_f32_16x16x32_bf16(
                        af[mi], bfr[ni], acc[mi][ni], 0, 0, 0);
        }
        __builtin_amdgcn_s_setprio(0);
        __syncthreads();                           // drains vmcnt (next tile) + lgkm
        buf ^= 1;
    }

#pragma unroll
    for (int mi = 0; mi < 4; mi++)
#pragma unroll
        for (int ni = 0; ni < 4; ni++)
#pragma unroll
            for (int r = 0; r < 4; r++) {
                int m = brow + wr * 64 + mi * 16 + lg * 4 + r;
                int n = bcol + wc * 64 + ni * 16 + lr;
                float v = acc[mi][ni][r];
                if (MODE == 0) {
                    int m3 = n >> 10, nn = n & 1023;
                    short* ob = m3 ? outb2 : outb;
                    int b = m >> 11, s = m & 2047, h = nn >> 6, hd = nn & 63;
                    ob[((size_t)(b * Hc + h) * Sc + s) * HDc + hd] = f2bf(v);
                } else if (MODE == 2) {
                    int h = m >> 6, hd = m & 63, b = n >> 11, s = n & 2047;
                    outb[((size_t)((b * Hc + h) * HDc + hd)) * Sc + s] = f2bf(v);
                } else {
                    v += bias[n];
                    if (!mask[m]) v = 0.f;
                    outf[(size_t)m * Dc + n] = v;
                }
            }
}

// ---------------- flash attention, swapped-operand 32x32, in-register softmax ------------
// 512 blocks = 64 bh x 8 pairs (XCD-swizzled: 8 consecutive bh per XCD).
// Block runs q-tiles p and 15-p (34 K-tiles). 4 waves x 32 q-rows.
// LDS double-buffered (32KB): one barrier per K-tile; ds_writes overlap MFMA.
// T13 defer-max: skip rescale unless any lane's tile-max exceeds mrow+44 (raw).
__global__ __launch_bounds__(256, 2) void attn_kernel(
    const short* __restrict__ Q, const short* __restrict__ Kp,
    const short* __restrict__ Vt, short* __restrict__ ctx) {
    __shared__ __attribute__((aligned(16))) short smem[16384];  // buf b: K @ b*8192, V @ b*8192+4096
    int bid = blockIdx.x;
    int swz = (bid & 7) * 64 + (bid >> 3);
    int p = swz & 7, bh = swz >> 3;
    const short* qp  = Q  + (size_t)bh * Sc * HDc;
    const short* kpb = Kp + (size_t)bh * Sc * HDc;
    const short* vpb = Vt + (size_t)bh * HDc * Sc;
    int t = threadIdx.x, w = t >> 6, l = t & 63;
    int la31 = l & 31, hi = l >> 5, hi4 = hi * 4;
    int b = bh >> 4, h = bh & 15;
    const float cexp = 0.125f * 1.44269504088896f;   // (1/sqrt(64)) * log2(e)

    // staging chunk constants: chunk c0=t (keys/hds 0..31), c1=t+256 (32..63)
    int co  = t & 31;
    int cin = ((t >> 6) & 3) * 16 + ((t >> 5) & 1) * 8;

    for (int ph = 0; ph < 2; ph++) {
        int qt = ph == 0 ? p : 15 - p;
        int qbase = qt * 128;
        int wq = qbase + w * 32;
        int qla = wq + la31;
        int nt = qbase / 64 + 2;

        bf16x8 qf[4];
#pragma unroll
        for (int m16 = 0; m16 < 4; m16++)
            qf[m16] = *(const bf16x8*)&qp[(size_t)qla * HDc + m16 * 16 + hi * 8];

        f32x16 o0, o1;
#pragma unroll
        for (int r = 0; r < 16; r++) { o0[r] = 0.f; o1[r] = 0.f; }
        float mrow = -3e38f, lrow = 0.f, mc = mrow * cexp;

        // incremental staging pointers (tile 0)
        const short* ks0 = kpb + co * HDc + cin;
        const short* ks1 = kpb + (32 + co) * HDc + cin;
        const short* vs0 = vpb + (size_t)co * Sc + cin;
        const short* vs1 = vpb + (size_t)(32 + co) * Sc + cin;

        bf16x8 rk0 = *(const bf16x8*)ks0, rk1 = *(const bf16x8*)ks1;
        bf16x8 rv0 = *(const bf16x8*)vs0, rv1 = *(const bf16x8*)vs1;
        ks0 += 64 * HDc; ks1 += 64 * HDc; vs0 += 64; vs1 += 64;

        __syncthreads();                             // prev phase fully done with smem
        *(bf16x8*)&smem[t * 8]                = rk0;
        *(bf16x8*)&smem[(t + 256) * 8]        = rk1;
        *(bf16x8*)&smem[4096 + t * 8]         = rv0;
        *(bf16x8*)&smem[4096 + (t + 256) * 8] = rv1;
        if (nt > 1) {
            rk0 = *(const bf16x8*)ks0; rk1 = *(const bf16x8*)ks1;
            rv0 = *(const bf16x8*)vs0; rv1 = *(const bf16x8*)vs1;
            ks0 += 64 * HDc; ks1 += 64 * HDc; vs0 += 64; vs1 += 64;
        }

        int buf = 0;
        for (int tk = 0; tk < nt; tk++) {
            int k0 = tk * 64;
            __syncthreads();                         // buf (tile tk) visible
            int ob = (buf ^ 1) * 8192;
            if (tk + 1 < nt) {                       // write tile tk+1 (overlaps compute)
                *(bf16x8*)&smem[ob + t * 8]                = rk0;
                *(bf16x8*)&smem[ob + (t + 256) * 8]        = rk1;
                *(bf16x8*)&smem[ob + 4096 + t * 8]         = rv0;
                *(bf16x8*)&smem[ob + 4096 + (t + 256) * 8] = rv1;
            }
            if (tk + 2 < nt) {                       // load tile tk+2 into regs
                rk0 = *(const bf16x8*)ks0; rk1 = *(const bf16x8*)ks1;
                rv0 = *(const bf16x8*)vs0; rv1 = *(const bf16x8*)vs1;
                ks0 += 64 * HDc; ks1 += 64 * HDc; vs0 += 64; vs1 += 64;
            }
            if (k0 <= wq + 31) {                     // wave-uniform causal skip
                int bb = buf * 8192;
                // ---- S^T = K Q^T
                f32x16 s0, s1;
#pragma unroll
                for (int r = 0; r < 16; r++) { s0[r] = 0.f; s1[r] = 0.f; }
                __builtin_amdgcn_s_setprio(1);
#pragma unroll
                for (int m16 = 0; m16 < 4; m16++) {
                    bf16x8 kf0 = *(const bf16x8*)&smem[bb + ((m16 * 2 + hi) * 32 + la31) * 8];
                    bf16x8 kf1 = *(const bf16x8*)&smem[bb + (((4 + m16) * 2 + hi) * 32 + la31) * 8];
                    s0 = __builtin_amdgcn_mfma_f32_32x32x16_bf16(kf0, qf[m16], s0, 0, 0, 0);
                    s1 = __builtin_amdgcn_mfma_f32_32x32x16_bf16(kf1, qf[m16], s1, 0, 0, 0);
                }
                __builtin_amdgcn_s_setprio(0);

                // ---- online softmax with defer-max (T13)
                float pm = -3e38f;
                if (k0 + 64 > wq) {                  // diagonal: causal mask
#pragma unroll
                    for (int r = 0; r < 16; r++) {
                        int key = k0 + ((r & 3) + 8 * (r >> 2)) + hi4;
                        float a0 = (key      <= qla) ? s0[r] : -3e38f; s0[r] = a0;
                        float a1 = (key + 32 <= qla) ? s1[r] : -3e38f; s1[r] = a1;
                        pm = fmaxf(pm, fmaxf(a0, a1));
                    }
                } else {
#pragma unroll
                    for (int r = 0; r < 16; r++) pm = fmaxf(pm, fmaxf(s0[r], s1[r]));
                }
                if (__any(pm > mrow + 44.0f)) {      // rescale path (rare after tile 0)
                    float mx = pair_max(pm);
                    float mnew = fmaxf(mrow, mx);
                    float corr = exp2f((mrow - mnew) * cexp);
                    mrow = mnew; mc = mnew * cexp;
                    lrow *= corr;
#pragma unroll
                    for (int r = 0; r < 16; r++) { o0[r] *= corr; o1[r] *= corr; }
                }
                float sum = 0.f;
#pragma unroll
                for (int r = 0; r < 16; r++) {
                    float p0 = exp2f(fmaf(s0[r], cexp, -mc)); s0[r] = p0;
                    float p1 = exp2f(fmaf(s1[r], cexp, -mc)); s1[r] = p1;
                    sum += p0 + p1;
                }
                lrow += pair_sum(sum);

                // ---- O^T += V^T P^T
                union U { unsigned u[4]; bf16x8 v; };
                __builtin_amdgcn_s_setprio(1);
#define PVSTEP(SP, KS, KS2) do {                                                   \
                    unsigned w0 = cvt_pk_bf16(SP[8*(KS2)+0], SP[8*(KS2)+1]);       \
                    unsigned w1 = cvt_pk_bf16(SP[8*(KS2)+2], SP[8*(KS2)+3]);       \
                    unsigned x0 = cvt_pk_bf16(SP[8*(KS2)+4], SP[8*(KS2)+5]);       \
                    unsigned x1 = cvt_pk_bf16(SP[8*(KS2)+6], SP[8*(KS2)+7]);       \
                    uint2v r0 = __builtin_amdgcn_permlane32_swap(w0, x0, false, false); \
                    uint2v r1 = __builtin_amdgcn_permlane32_swap(w1, x1, false, false); \
                    U pu; pu.u[0] = r0[0]; pu.u[1] = r1[0]; pu.u[2] = r0[1]; pu.u[3] = r1[1]; \
                    bf16x8 av0 = *(const bf16x8*)&smem[bb + 4096 + (((KS) * 2 + hi) * 32 + la31) * 8];       \
                    bf16x8 av1 = *(const bf16x8*)&smem[bb + 4096 + (((4 + (KS)) * 2 + hi) * 32 + la31) * 8]; \
                    o0 = __builtin_amdgcn_mfma_f32_32x32x16_bf16(av0, pu.v, o0, 0, 0, 0);        \
                    o1 = __builtin_amdgcn_mfma_f32_32x32x16_bf16(av1, pu.v, o1, 0, 0, 0);        \
                } while (0)
                PVSTEP(s0, 0, 0); PVSTEP(s0, 1, 1); PVSTEP(s1, 2, 0); PVSTEP(s1, 3, 1);
#undef PVSTEP
                __builtin_amdgcn_s_setprio(0);
            }
            buf ^= 1;
        }

        // ---- epilogue: O^T regs -> per-warp LDS transpose -> vectorized global store
        __syncthreads();                            // all waves done with stage buffers
        float rl = 1.0f / lrow;
        short* ep = &smem[w * 2304];                // [32 q][72] per warp
#pragma unroll
        for (int r = 0; r < 16; r++) {
            int hd = (r & 3) + 8 * (r >> 2) + hi4;
            ep[la31 * 72 + hd]      = f2bf(o0[r] * rl);
            ep[la31 * 72 + 32 + hd] = f2bf(o1[r] * rl);
        }
        asm volatile("s_waitcnt lgkmcnt(0)" ::: "memory");
        __builtin_amdgcn_sched_barrier(0);
        int erow = l >> 1, ecol = (l & 1) * 32;
        size_t gbase = ((size_t)(b * Sc + wq + erow)) * Dc + h * 64 + ecol;
#pragma unroll
        for (int i2 = 0; i2 < 4; i2++)
            *(bf16x8*)&ctx[gbase + i2 * 8] = *(const bf16x8*)&ep[erow * 72 + ecol + i2 * 8];
    }
}

// ---------------- launch ----------------

extern "C" void kernel_launch(void* const* d_in, const int* in_sizes, int n_in,
                              void* d_out, int out_size, void* d_ws, size_t ws_size,
                              hipStream_t stream) {
    (void)in_sizes; (void)n_in; (void)out_size; (void)ws_size;
    const float* x  = (const float*)d_in[0];
    const float* Wq = (const float*)d_in[1];
    const float* Wk = (const float*)d_in[2];
    const float* Wv = (const float*)d_in[3];
    const float* Wo = (const float*)d_in[4];
    const float* bo = (const float*)d_in[5];
    const unsigned int* vm = (const unsigned int*)d_in[6];

    char* ws = (char*)d_ws;
    short* xb  = (short*)(ws);                       // 16 MB  x bf16 [8192][1024]
    short* Wt  = (short*)(ws + (16u << 20));         //  8 MB  Wt bf16 [4][1024][1024]
    short* qb  = (short*)(ws + (24u << 20));         // 16 MB  [B,H,S,HD]
    short* kb  = (short*)(ws + (40u << 20));         // 16 MB  [B,H,S,HD]
    short* vt  = (short*)(ws + (56u << 20));         // 16 MB  [B,H,HD,S]  (V^T)
    short* ctx = (short*)(ws + (72u << 20));         // 16 MB  [8192][1024]
    unsigned char* mask8 = (unsigned char*)(ws + (88u << 20));   // 8 KB

    cast_x_kernel<<<4096, 256, 0, stream>>>(x, xb);
    transpose_w_kernel<<<dim3(16, 16, 4), 256, 0, stream>>>(Wq, Wk, Wv, Wo, Wt);
    mask_kernel<<<32, 256, 0, stream>>>(vm, mask8);

    // fused Q+K projection (Bt = Wq|Wk contiguous, N=2048)
    gemm_bt<0><<<1024, 256, 0, stream>>>(xb, Wt, nullptr, nullptr, qb, kb, nullptr);
    // V^T = Wv^T (as A) x x (as B): stored [B,H,HD,S]
    gemm_bt<2><<<512, 256, 0, stream>>>(Wt + 2 * 1048576, xb, nullptr, nullptr, vt, nullptr, nullptr);

    attn_kernel<<<512, 256, 0, stream>>>(qb, kb, vt, ctx);

    gemm_bt<1><<<512, 256, 0, stream>>>(ctx, Wt + 3 * 1048576, bo, mask8, nullptr, nullptr, (float*)d_out);
}

// Round 6
// 198.191 us; speedup vs baseline: 1.8572x; 1.0306x over previous
//
#include <hip/hip_runtime.h>

// Causal MHA, bf16 MFMA pipeline. B=4 S=2048 D=1024 H=16 HD=64. Out f32 [B,S,D].
// R5: attention restructured for critical-path + TLP: 512-thread blocks
//     (8 waves = 4 q-subgroups x 2 key-halves). Each wave does a 32q x 32k
//     sub-tile per K-tile (half the per-wave serial work), partial (m,l,O)
//     per key-half, LDS log-sum-exp merge per phase. 2 blocks/CU = 16 waves/CU.

typedef __attribute__((ext_vector_type(8))) short bf16x8;
typedef __attribute__((ext_vector_type(4))) float f32x4;
typedef __attribute__((ext_vector_type(16))) float f32x16;
typedef __attribute__((ext_vector_type(2))) unsigned uint2v;

static __device__ __forceinline__ short f2bf(float f) {
    union { float f; unsigned u; } x; x.f = f;
    unsigned r = (x.u + 0x7FFFu + ((x.u >> 16) & 1u)) >> 16;   // RNE
    return (short)r;
}

__device__ __forceinline__ void gload_lds16(const void* g, void* lds) {
    __builtin_amdgcn_global_load_lds(
        (const __attribute__((address_space(1))) unsigned int*)g,
        (__attribute__((address_space(3))) unsigned int*)lds, 16, 0, 0);
}

__device__ __forceinline__ unsigned cvt_pk_bf16(float lo, float hi) {
    unsigned r;
    asm volatile("v_cvt_pk_bf16_f32 %0, %1, %2" : "=v"(r) : "v"(lo), "v"(hi));
    return r;
}

__device__ __forceinline__ float pair_max(float x) {       // max with lane^32
    union { float f; unsigned u; } c; c.f = x;
    uint2v r = __builtin_amdgcn_permlane32_swap(c.u, c.u, false, false);
    union { unsigned u; float f; } a, b; a.u = r[0]; b.u = r[1];
    return fmaxf(a.f, b.f);
}

__device__ __forceinline__ float pair_sum(float x) {       // sum with lane^32
    union { float f; unsigned u; } c; c.f = x;
    uint2v r = __builtin_amdgcn_permlane32_swap(c.u, c.u, false, false);
    union { unsigned u; float f; } a, b; a.u = r[0]; b.u = r[1];
    return a.f + b.f;
}

constexpr int Bc = 4, Sc = 2048, Dc = 1024, Hc = 16, HDc = 64;

// ---------------- prep kernels ----------------

__global__ void cast_x_kernel(const float* __restrict__ x, short* __restrict__ xb) {
    int i = blockIdx.x * blockDim.x + threadIdx.x;
    const float4* xin = (const float4*)x;
    float4 a = xin[i * 2 + 0];
    float4 b = xin[i * 2 + 1];
    bf16x8 o;
    o[0] = f2bf(a.x); o[1] = f2bf(a.y); o[2] = f2bf(a.z); o[3] = f2bf(a.w);
    o[4] = f2bf(b.x); o[5] = f2bf(b.y); o[6] = f2bf(b.z); o[7] = f2bf(b.w);
    *(bf16x8*)&xb[(size_t)i * 8] = o;
}

__global__ void transpose_w_kernel(const float* __restrict__ W0, const float* __restrict__ W1,
                                   const float* __restrict__ W2, const float* __restrict__ W3,
                                   short* __restrict__ Wt) {
    __shared__ float tile[64][65];
    const float* W = blockIdx.z == 0 ? W0 : blockIdx.z == 1 ? W1 : blockIdx.z == 2 ? W2 : W3;
    short* out = Wt + (size_t)blockIdx.z * Dc * Dc;
    int k0 = blockIdx.y * 64, n0 = blockIdx.x * 64;
    int t = threadIdx.x;
#pragma unroll
    for (int i = 0; i < 4; i++) {
        int c = t + i * 256; int r = c >> 4, cc = (c & 15) * 4;
        float4 v = *(const float4*)&W[(size_t)(k0 + r) * Dc + n0 + cc];
        tile[r][cc + 0] = v.x; tile[r][cc + 1] = v.y;
        tile[r][cc + 2] = v.z; tile[r][cc + 3] = v.w;
    }
    __syncthreads();
#pragma unroll
    for (int i = 0; i < 2; i++) {
        int c = t + i * 256; int nn = c >> 3, kc = (c & 7) * 8;
        bf16x8 o;
#pragma unroll
        for (int j = 0; j < 8; j++) o[j] = f2bf(tile[kc + j][nn]);
        *(bf16x8*)&out[(size_t)(n0 + nn) * Dc + k0 + kc] = o;
    }
}

__global__ void mask_kernel(const unsigned int* __restrict__ m, unsigned char* __restrict__ mask8) {
    int i = blockIdx.x * blockDim.x + threadIdx.x;
    unsigned w0 = m[0];
    unsigned char v;
    if (w0 == 1u)                 v = (unsigned char)(m[i] != 0);
    else if (w0 == 0x01010101u)   v = ((const unsigned char*)m)[i];
    else                          v = (((const float*)m)[i] != 0.0f);
    mask8[i] = v ? 1 : 0;
}

// ---------------- GEMM: D[m][n] = sum_k A[m][k] * Bt[n][k], K=1024 ----------------
// Double-buffered global_load_lds staging, 1 barrier per K-step.
// MODE 0: fused Q+K (Bt rows 0..2047 = Wq|Wk), store bf16 [B,H,S,HD] to outb/outb2.
// MODE 1: +bias, row-mask, f32 out.   MODE 2: V^T, store bf16 [B,H,HD,S].
template <int MODE>
__global__ __launch_bounds__(256, 2) void gemm_bt(
    const short* __restrict__ A, const short* __restrict__ Bt,
    const float* __restrict__ bias, const unsigned char* __restrict__ mask,
    short* __restrict__ outb, short* __restrict__ outb2, float* __restrict__ outf) {
    constexpr int K = 1024;
    __shared__ __attribute__((aligned(16))) short la[2][128 * 64];
    __shared__ __attribute__((aligned(16))) short lb[2][128 * 64];
    int bid = blockIdx.x;
    int swz = (bid & 7) * (gridDim.x >> 3) + (bid >> 3);   // XCD-contiguous chunks
    int tm, tn;
    if (MODE == 0)      { tm = swz >> 4; tn = swz & 15; }  // 64 x 16 tiles (N=2048)
    else if (MODE == 2) { tm = swz & 7;  tn = swz >> 3; }  // 8 x 64
    else                { tm = swz >> 3; tn = swz & 7;  }  // 64 x 8
    int brow = tm * 128, bcol = tn * 128;
    int t = threadIdx.x;
    int w = t >> 6, l = t & 63;
    int wr = w >> 1, wc = w & 1;
    int lr = l & 15, lg = l >> 4;
    int lrow8 = l >> 3, lcol = (l & 7) * 8;

    f32x4 zero4 = {0.f, 0.f, 0.f, 0.f};
    f32x4 acc[4][4];
#pragma unroll
    for (int mi = 0; mi < 4; mi++)
#pragma unroll
        for (int ni = 0; ni < 4; ni++) acc[mi][ni] = zero4;

    auto stage = [&](int bufi, int kt) {
#pragma unroll
        for (int i = 0; i < 4; i++) {
            int seg = w * 4 + i;
            int row = seg * 8 + lrow8;
            gload_lds16(&A [(size_t)(brow + row) * K + kt + lcol], &la[bufi][seg * 512]);
            gload_lds16(&Bt[(size_t)(bcol + row) * K + kt + lcol], &lb[bufi][seg * 512]);
        }
    };

    stage(0, 0);
    __syncthreads();                               // buf0 ready
    int buf = 0;
    for (int kt = 0; kt < K; kt += 64) {
        if (kt + 64 < K) stage(buf ^ 1, kt + 64);  // async loads overlap compute
        __builtin_amdgcn_s_setprio(1);
#pragma unroll
        for (int kk = 0; kk < 2; kk++) {
            bf16x8 af[4], bfr[4];
#pragma unroll
            for (int mi = 0; mi < 4; mi++)
                af[mi] = *(const bf16x8*)&la[buf][(wr * 64 + mi * 16 + lr) * 64 + kk * 32 + lg * 8];
#pragma unroll
            for (int ni = 0; ni < 4; ni++)
                bfr[ni] = *(const bf16x8*)&lb[buf][(wc * 64 + ni * 16 + lr) * 64 + kk * 32 + lg * 8];
#pragma unroll
            for (int mi = 0; mi < 4; mi++)
#pragma unroll
                for (int ni = 0; ni < 4; ni++)
                    acc[mi][ni] = __builtin_amdgcn_mfma_f32_16x16x32_bf16(
                        af[mi], bfr[ni], acc[mi][ni], 0, 0, 0);
        }
        __builtin_amdgcn_s_setprio(0);
        __syncthreads();                           // drains vmcnt (next tile) + lgkm
        buf ^= 1;
    }

#pragma unroll
    for (int mi = 0; mi < 4; mi++)
#pragma unroll
        for (int ni = 0; ni < 4; ni++)
#pragma unroll
            for (int r = 0; r < 4; r++) {
                int m = brow + wr * 64 + mi * 16 + lg * 4 + r;
                int n = bcol + wc * 64 + ni * 16 + lr;
                float v = acc[mi][ni][r];
                if (MODE == 0) {
                    int m3 = n >> 10, nn = n & 1023;
                    short* ob = m3 ? outb2 : outb;
                    int b = m >> 11, s = m & 2047, h = nn >> 6, hd = nn & 63;
                    ob[((size_t)(b * Hc + h) * Sc + s) * HDc + hd] = f2bf(v);
                } else if (MODE == 2) {
                    int h = m >> 6, hd = m & 63, b = n >> 11, s = n & 2047;
                    outb[((size_t)((b * Hc + h) * HDc + hd)) * Sc + s] = f2bf(v);
                } else {
                    v += bias[n];
                    if (!mask[m]) v = 0.f;
                    outf[(size_t)m * Dc + n] = v;
                }
            }
}

// ---------------- flash attention: key-split waves, in-register softmax ----------------
// 512 blocks = 64 bh x 8 pairs (XCD-swizzled). Block = 512 threads = 8 waves:
// qg = w&3 (q rows qbase+qg*32..+32), h2 = w>>2 (key half of each 64-key tile).
// Per tile each wave: 32q x 32k scores (16/lane), own partial (m,l,O).
// Per-phase LDS merge (log-sum-exp) combines the two key halves.
__global__ __launch_bounds__(512, 4) void attn_kernel(
    const short* __restrict__ Q, const short* __restrict__ Kp,
    const short* __restrict__ Vt, short* __restrict__ ctx) {
    // [0,16384): stage dbuf (buf b: K @ b*8192, V @ b*8192+4096); epilogue overlays.
    // floats @ short 16384: lo[4*64*33]; floats @ short 33280: lm[4*64*2]
    __shared__ __attribute__((aligned(16))) short smem[34304];
    float* lo = (float*)&smem[16384];
    float* lm = (float*)&smem[33280];
    int bid = blockIdx.x;
    int swz = (bid & 7) * 64 + (bid >> 3);
    int p = swz & 7, bh = swz >> 3;
    const short* qp  = Q  + (size_t)bh * Sc * HDc;
    const short* kpb = Kp + (size_t)bh * Sc * HDc;
    const short* vpb = Vt + (size_t)bh * HDc * Sc;
    int t = threadIdx.x, w = t >> 6, l = t & 63;
    int qg = w & 3, h2 = w >> 2;
    int la31 = l & 31, hi = l >> 5, hi4 = hi * 4;
    int b = bh >> 4, h = bh & 15;
    const float cexp = 0.125f * 1.44269504088896f;   // (1/sqrt(64)) * log2(e)

    // one 16B K-chunk + one 16B V-chunk per thread (512 chunks each)
    int ck  = t & 31;                                // key/hd within half
    int cin = ((t >> 6) & 3) * 16 + ((t >> 5) & 1) * 8;
    int chalf = (t >> 8) & 1;

    for (int ph = 0; ph < 2; ph++) {
        int qt = ph == 0 ? p : 15 - p;
        int qbase = qt * 128;
        int wq = qbase + qg * 32;
        int qla = wq + la31;
        int nt = qbase / 64 + 2;

        bf16x8 qf[4];
#pragma unroll
        for (int m16 = 0; m16 < 4; m16++)
            qf[m16] = *(const bf16x8*)&qp[(size_t)qla * HDc + m16 * 16 + hi * 8];

        f32x16 o0, o1;
#pragma unroll
        for (int r = 0; r < 16; r++) { o0[r] = 0.f; o1[r] = 0.f; }
        float mrow = -3e38f, lrow = 0.f, mc = mrow * cexp;

        // incremental staging pointers (tile 0)
        const short* ks = kpb + (chalf * 32 + ck) * HDc + cin;
        const short* vs = vpb + (size_t)(chalf * 32 + ck) * Sc + cin;

        bf16x8 rk = *(const bf16x8*)ks, rv = *(const bf16x8*)vs;
        ks += 64 * HDc; vs += 64;

        __syncthreads();                             // prev phase fully done with smem
        *(bf16x8*)&smem[t * 8]        = rk;
        *(bf16x8*)&smem[4096 + t * 8] = rv;
        rk = *(const bf16x8*)ks; rv = *(const bf16x8*)vs;   // tile 1 (nt >= 2 always)
        ks += 64 * HDc; vs += 64;

        int buf = 0;
        for (int tk = 0; tk < nt; tk++) {
            int k0 = tk * 64;
            __syncthreads();                         // buf (tile tk) visible
            int ob = (buf ^ 1) * 8192;
            if (tk + 1 < nt) {                       // write tile tk+1 (overlaps compute)
                *(bf16x8*)&smem[ob + t * 8]        = rk;
                *(bf16x8*)&smem[ob + 4096 + t * 8] = rv;
            }
            if (tk + 2 < nt) {                       // load tile tk+2 into regs
                rk = *(const bf16x8*)ks; rv = *(const bf16x8*)vs;
                ks += 64 * HDc; vs += 64;
            }
            int k0h = k0 + h2 * 32;                  // this wave's key base
            if (k0h <= wq + 31) {                    // wave-uniform causal skip
                int bb = buf * 8192;
                // ---- S^T(32k x 32q) = K_half Q^T
                f32x16 s;
#pragma unroll
                for (int r = 0; r < 16; r++) s[r] = 0.f;
                __builtin_amdgcn_s_setprio(1);
#pragma unroll
                for (int m16 = 0; m16 < 4; m16++) {
                    bf16x8 kf = *(const bf16x8*)&smem[bb + (((h2 * 4 + m16) * 2 + hi) * 32 + la31) * 8];
                    s = __builtin_amdgcn_mfma_f32_32x32x16_bf16(kf, qf[m16], s, 0, 0, 0);
                }
                __builtin_amdgcn_s_setprio(0);

                // ---- mask (diagonal sub-tiles only) + per-lane max (tree)
                if (k0h + 31 > wq) {
#pragma unroll
                    for (int r = 0; r < 16; r++) {
                        int key = k0h + ((r & 3) + 8 * (r >> 2)) + hi4;
                        s[r] = (key <= qla) ? s[r] : -3e38f;
                    }
                }
                float m0 = fmaxf(fmaxf(fmaxf(s[0], s[1]), fmaxf(s[2], s[3])),
                                 fmaxf(fmaxf(s[4], s[5]), fmaxf(s[6], s[7])));
                float m1 = fmaxf(fmaxf(fmaxf(s[8], s[9]), fmaxf(s[10], s[11])),
                                 fmaxf(fmaxf(s[12], s[13]), fmaxf(s[14], s[15])));
                float pm = fmaxf(m0, m1);
                if (__any(pm > mrow + 44.0f)) {      // rescale path (rare after 1st tile)
                    float mx = pair_max(pm);
                    float mnew = fmaxf(mrow, mx);
                    float corr = exp2f((mrow - mnew) * cexp);
                    mrow = mnew; mc = mnew * cexp;
                    lrow *= corr;
#pragma unroll
                    for (int r = 0; r < 16; r++) { o0[r] *= corr; o1[r] *= corr; }
                }
#pragma unroll
                for (int r = 0; r < 16; r++) s[r] = exp2f(fmaf(s[r], cexp, -mc));
                float s0q = (s[0] + s[1]) + (s[2] + s[3]);
                float s1q = (s[4] + s[5]) + (s[6] + s[7]);
                float s2q = (s[8] + s[9]) + (s[10] + s[11]);
                float s3q = (s[12] + s[13]) + (s[14] + s[15]);
                lrow += pair_sum((s0q + s1q) + (s2q + s3q));

                // ---- O^T += V^T_half P^T_half (KS = 2*h2 + KS2)
                union U { unsigned u[4]; bf16x8 v; };
                __builtin_amdgcn_s_setprio(1);
#define PVSTEP(KS, KS2) do {                                                       \
                    unsigned w0 = cvt_pk_bf16(s[8*(KS2)+0], s[8*(KS2)+1]);         \
                    unsigned w1 = cvt_pk_bf16(s[8*(KS2)+2], s[8*(KS2)+3]);         \
                    unsigned x0 = cvt_pk_bf16(s[8*(KS2)+4], s[8*(KS2)+5]);         \
                    unsigned x1 = cvt_pk_bf16(s[8*(KS2)+6], s[8*(KS2)+7]);         \
                    uint2v r0 = __builtin_amdgcn_permlane32_swap(w0, x0, false, false); \
                    uint2v r1 = __builtin_amdgcn_permlane32_swap(w1, x1, false, false); \
                    U pu; pu.u[0] = r0[0]; pu.u[1] = r1[0]; pu.u[2] = r0[1]; pu.u[3] = r1[1]; \
                    bf16x8 av0 = *(const bf16x8*)&smem[bb + 4096 + ((((KS)) * 2 + hi) * 32 + la31) * 8];     \
                    bf16x8 av1 = *(const bf16x8*)&smem[bb + 4096 + (((4 + (KS)) * 2 + hi) * 32 + la31) * 8]; \
                    o0 = __builtin_amdgcn_mfma_f32_32x32x16_bf16(av0, pu.v, o0, 0, 0, 0);        \
                    o1 = __builtin_amdgcn_mfma_f32_32x32x16_bf16(av1, pu.v, o1, 0, 0, 0);        \
                } while (0)
                PVSTEP(2 * h2 + 0, 0); PVSTEP(2 * h2 + 1, 1);
#undef PVSTEP
                __builtin_amdgcn_s_setprio(0);
            }
            buf ^= 1;
        }

        // ---- merge the two key-halves (waves h2=1 publish, h2=0 combine)
        __syncthreads();                            // all waves done with stage bufs
        int mbase = (qg * 64 + l) * 33;
        if (h2 == 1) {
#pragma unroll
            for (int r = 0; r < 16; r++) {
                lo[mbase + r]      = o0[r];
                lo[mbase + 16 + r] = o1[r];
            }
            lm[(qg * 64 + l) * 2 + 0] = mrow;
            lm[(qg * 64 + l) * 2 + 1] = lrow;
        }
        __syncthreads();
        if (h2 == 0) {
            float mb = lm[(qg * 64 + l) * 2 + 0];
            float lb = lm[(qg * 64 + l) * 2 + 1];
            float ms = fmaxf(mrow, mb);
            float ca = exp2f((mrow - ms) * cexp);
            float cb = exp2f((mb - ms) * cexp);
            float lsum = lrow * ca + lb * cb;
            float rl = 1.0f / lsum;
            // epilogue: combined O -> per-warp LDS transpose -> vectorized store
            short* ep = &smem[qg * 2304];            // [32 q][72]
#pragma unroll
            for (int r = 0; r < 16; r++) {
                int hd = (r & 3) + 8 * (r >> 2) + hi4;
                float v0 = (o0[r] * ca + lo[mbase + r]      * cb) * rl;
                float v1 = (o1[r] * ca + lo[mbase + 16 + r] * cb) * rl;
                ep[la31 * 72 + hd]      = f2bf(v0);
                ep[la31 * 72 + 32 + hd] = f2bf(v1);
            }
            asm volatile("s_waitcnt lgkmcnt(0)" ::: "memory");
            __builtin_amdgcn_sched_barrier(0);
            int erow = l >> 1, ecol = (l & 1) * 32;
            size_t gbase = ((size_t)(b * Sc + wq + erow)) * Dc + h * 64 + ecol;
#pragma unroll
            for (int i2 = 0; i2 < 4; i2++)
                *(bf16x8*)&ctx[gbase + i2 * 8] = *(const bf16x8*)&ep[erow * 72 + ecol + i2 * 8];
        }
    }
}

// ---------------- launch ----------------

extern "C" void kernel_launch(void* const* d_in, const int* in_sizes, int n_in,
                              void* d_out, int out_size, void* d_ws, size_t ws_size,
                              hipStream_t stream) {
    (void)in_sizes; (void)n_in; (void)out_size; (void)ws_size;
    const float* x  = (const float*)d_in[0];
    const float* Wq = (const float*)d_in[1];
    const float* Wk = (const float*)d_in[2];
    const float* Wv = (const float*)d_in[3];
    const float* Wo = (const float*)d_in[4];
    const float* bo = (const float*)d_in[5];
    const unsigned int* vm = (const unsigned int*)d_in[6];

    char* ws = (char*)d_ws;
    short* xb  = (short*)(ws);                       // 16 MB  x bf16 [8192][1024]
    short* Wt  = (short*)(ws + (16u << 20));         //  8 MB  Wt bf16 [4][1024][1024]
    short* qb  = (short*)(ws + (24u << 20));         // 16 MB  [B,H,S,HD]
    short* kb  = (short*)(ws + (40u << 20));         // 16 MB  [B,H,S,HD]
    short* vt  = (short*)(ws + (56u << 20));         // 16 MB  [B,H,HD,S]  (V^T)
    short* ctx = (short*)(ws + (72u << 20));         // 16 MB  [8192][1024]
    unsigned char* mask8 = (unsigned char*)(ws + (88u << 20));   // 8 KB

    cast_x_kernel<<<4096, 256, 0, stream>>>(x, xb);
    transpose_w_kernel<<<dim3(16, 16, 4), 256, 0, stream>>>(Wq, Wk, Wv, Wo, Wt);
    mask_kernel<<<32, 256, 0, stream>>>(vm, mask8);

    // fused Q+K projection (Bt = Wq|Wk contiguous, N=2048)
    gemm_bt<0><<<1024, 256, 0, stream>>>(xb, Wt, nullptr, nullptr, qb, kb, nullptr);
    // V^T = Wv^T (as A) x x (as B): stored [B,H,HD,S]
    gemm_bt<2><<<512, 256, 0, stream>>>(Wt + 2 * 1048576, xb, nullptr, nullptr, vt, nullptr, nullptr);

    attn_kernel<<<512, 512, 0, stream>>>(qb, kb, vt, ctx);

    gemm_bt<1><<<512, 256, 0, stream>>>(ctx, Wt + 3 * 1048576, bo, mask8, nullptr, nullptr, (float*)d_out);
}